// Round 2
// baseline (673.912 us; speedup 1.0000x reference)
//
#include <hip/hip_runtime.h>

// SlotAttention MI355X implementation, v2.
// k0: pre-pack Wk|Wv into MFMA B-fragment lane order (bf16, L2-resident).
// k1: LN(inputs) -> fragment-ordered LDS -> MFMA vs prepacked weights -> k[b][n][c], vT[b][c][n].
// kq: q from initial slots. Then 3x { k2: fused dots/softmax/renorm partial accumulate
// (per-wave partials straight to global, no block reduction); kr: reduce partials -> updates;
// k3: GRU + MLP -> new slots (+ q for next iter) }.
// Workspace (~289.2 MiB):
//   kmat  bf16 [32][16384][128]      @ 0
//   vT    bf16 [32][128][16384]      @ 134217728
//   qbuf  bf16 [32][16][128]         @ 268435456
//   wpk   bf16 [2][8][4][64][8]      @ 268566528
//   nump  f32  [32][32][4][16][128]  @ 268632064
//   denp  f32  [32][32][4][16]       @ 302186496
//   upd   f32  [32][16][128]         @ 302710784
//   sbuf  f32  [32][16][128]         @ 302972928

#define NTOT 16384
#define CDIM 128

using short8 = __attribute__((ext_vector_type(8))) short;
using f32x4  = __attribute__((ext_vector_type(4))) float;

__device__ __forceinline__ unsigned short f2bf(float x) {
  union { float f; unsigned u; } v; v.f = x;
  unsigned r = v.u + 0x7FFFu + ((v.u >> 16) & 1u);
  return (unsigned short)(r >> 16);
}
__device__ __forceinline__ float sigf(float x) { return 1.f / (1.f + __expf(-x)); }
__device__ __forceinline__ float tanhfast(float x) {
  x = fminf(fmaxf(x, -15.f), 15.f);
  float e = __expf(2.f * x);
  return (e - 1.f) / (e + 1.f);
}

// ---- K0: pre-pack weights into B-fragment lane order ----
// wpk[which][ct][kb][lane][j] = W[c_in = kb*32 + (lane>>4)*8 + j][c_out = ct*16 + (lane&15)]
__global__ __launch_bounds__(256) void k0_prep(const float* __restrict__ Wk,
    const float* __restrict__ Wv, unsigned short* __restrict__ wpk) {
  int idx = blockIdx.x * 256 + threadIdx.x;  // 0..32767
  int j = idx & 7, lane = (idx >> 3) & 63, kb = (idx >> 9) & 3,
      ct = (idx >> 11) & 7, which = idx >> 14;
  int lr = lane & 15, lg = lane >> 4;
  int cin = kb * 32 + lg * 8 + j, cout = ct * 16 + lr;
  const float* W = which ? Wv : Wk;
  wpk[idx] = f2bf(W[cin * 128 + cout]);
}

// ---- K1: LN(inputs) -> k, vT (MFMA against prepacked weights) ----
__global__ __launch_bounds__(256) void k1_lnkv(
    const float* __restrict__ in, const float* __restrict__ gam,
    const float* __restrict__ bet, const unsigned short* __restrict__ wpk,
    unsigned short* __restrict__ kmat, unsigned short* __restrict__ vT) {
  // fragment-ordered LDS: addr(row r, chunk kb, sub) = ((kb*4+sub)*64 + r) * 16 bytes
  __shared__ __align__(16) unsigned short xln[8192];  // 16 KB
  const int t = threadIdx.x, w = t >> 6, l = t & 63, lr = l & 15, lg = l >> 4;
  const long rowbase = (long)blockIdx.x * 64;

  // LayerNorm: wave w owns rows w*16..w*16+15; lane: lr = row, lg = 32-elem chunk
  {
    const float* src = in + (rowbase + w * 16 + lr) * CDIM + lg * 32;
    float x[32];
    #pragma unroll
    for (int i = 0; i < 8; ++i) {
      float4 v4 = ((const float4*)src)[i];
      x[i*4+0] = v4.x; x[i*4+1] = v4.y; x[i*4+2] = v4.z; x[i*4+3] = v4.w;
    }
    float s1 = 0.f, s2 = 0.f;
    #pragma unroll
    for (int i = 0; i < 32; ++i) { s1 += x[i]; s2 += x[i] * x[i]; }
    s1 += __shfl_xor(s1, 16); s1 += __shfl_xor(s1, 32);
    s2 += __shfl_xor(s2, 16); s2 += __shfl_xor(s2, 32);
    float mean = s1 * (1.f / 128.f);
    float var  = s2 * (1.f / 128.f) - mean * mean;
    float rstd = rsqrtf(var + 1e-5f);
    #pragma unroll
    for (int j = 0; j < 4; ++j) {
      f32x4 g0 = *(const f32x4*)(gam + lg * 32 + j * 8);
      f32x4 g1 = *(const f32x4*)(gam + lg * 32 + j * 8 + 4);
      f32x4 b0 = *(const f32x4*)(bet + lg * 32 + j * 8);
      f32x4 b1 = *(const f32x4*)(bet + lg * 32 + j * 8 + 4);
      short8 yv;
      #pragma unroll
      for (int i = 0; i < 4; ++i) {
        yv[i]     = (short)f2bf((x[j*8+i]   - mean) * rstd * g0[i] + b0[i]);
        yv[i + 4] = (short)f2bf((x[j*8+4+i] - mean) * rstd * g1[i] + b1[i]);
      }
      *(short8*)((char*)xln + ((lg * 4 + j) * 64 + (w * 16 + lr)) * 16) = yv;
    }
  }
  __syncthreads();

  // wave w covers row-tiles {rt0, rt0+1} x col-tiles {ct0..ct0+3}
  const int rt0 = (w >> 1) * 2, ct0 = (w & 1) * 4;
  short8 af[2][4];
  #pragma unroll
  for (int rtd = 0; rtd < 2; ++rtd)
    #pragma unroll
    for (int kb = 0; kb < 4; ++kb)
      af[rtd][kb] = *(const short8*)((const char*)xln +
                    ((kb * 4 + lg) * 64 + (rt0 + rtd) * 16 + lr) * 16);

  const long b = rowbase >> 14;
  // k pass
  #pragma unroll
  for (int cti = 0; cti < 4; ++cti) {
    int ct = ct0 + cti;
    f32x4 a0 = {0.f,0.f,0.f,0.f}, a1 = {0.f,0.f,0.f,0.f};
    #pragma unroll
    for (int kb = 0; kb < 4; ++kb) {
      short8 bf = *(const short8*)(wpk + ((ct * 4 + kb) * 64 + l) * 8);
      a0 = __builtin_amdgcn_mfma_f32_16x16x32_bf16(af[0][kb], bf, a0, 0, 0, 0);
      a1 = __builtin_amdgcn_mfma_f32_16x16x32_bf16(af[1][kb], bf, a1, 0, 0, 0);
    }
    #pragma unroll
    for (int r = 0; r < 4; ++r) {
      kmat[(rowbase + rt0 * 16 + lg * 4 + r) * CDIM + ct * 16 + lr] = f2bf(a0[r]);
      kmat[(rowbase + (rt0 + 1) * 16 + lg * 4 + r) * CDIM + ct * 16 + lr] = f2bf(a1[r]);
    }
  }
  // v pass (stored transposed: vT[b][c][n])
  unsigned short* vTb = vT + b * (CDIM * (long)NTOT);
  const long nloc = (rowbase & 16383) + rt0 * 16 + lg * 4;
  #pragma unroll
  for (int cti = 0; cti < 4; ++cti) {
    int ct = ct0 + cti;
    f32x4 a0 = {0.f,0.f,0.f,0.f}, a1 = {0.f,0.f,0.f,0.f};
    #pragma unroll
    for (int kb = 0; kb < 4; ++kb) {
      short8 bf = *(const short8*)(wpk + (((8 + ct) * 4 + kb) * 64 + l) * 8);
      a0 = __builtin_amdgcn_mfma_f32_16x16x32_bf16(af[0][kb], bf, a0, 0, 0, 0);
      a1 = __builtin_amdgcn_mfma_f32_16x16x32_bf16(af[1][kb], bf, a1, 0, 0, 0);
    }
    int c = ct * 16 + lr;
    ushort4 u0 = {f2bf(a0[0]), f2bf(a0[1]), f2bf(a0[2]), f2bf(a0[3])};
    ushort4 u1 = {f2bf(a1[0]), f2bf(a1[1]), f2bf(a1[2]), f2bf(a1[3])};
    *(ushort4*)(vTb + (long)c * NTOT + nloc) = u0;
    *(ushort4*)(vTb + (long)c * NTOT + nloc + 16) = u1;
  }
}

// ---- Kq: q = (LN_s(slots) @ Wq) / sqrt(C) -> bf16 (initial iteration) ----
__global__ __launch_bounds__(512) void kq_init(
    const float* __restrict__ slots, const float* __restrict__ lnsg,
    const float* __restrict__ lnsb, const float* __restrict__ Wq,
    unsigned short* __restrict__ qout) {
  const int b = blockIdx.x, t = threadIdx.x;
  const int s = t >> 5, jq = (t & 31) * 4;
  __shared__ __align__(16) float lnq[2048];
  f32x4 x4 = *(const f32x4*)(slots + b * 2048 + t * 4);
  float ps = x4[0] + x4[1] + x4[2] + x4[3];
  float pq = x4[0]*x4[0] + x4[1]*x4[1] + x4[2]*x4[2] + x4[3]*x4[3];
  ps += __shfl_xor(ps, 1); ps += __shfl_xor(ps, 2); ps += __shfl_xor(ps, 4); ps += __shfl_xor(ps, 8); ps += __shfl_xor(ps, 16);
  pq += __shfl_xor(pq, 1); pq += __shfl_xor(pq, 2); pq += __shfl_xor(pq, 4); pq += __shfl_xor(pq, 8); pq += __shfl_xor(pq, 16);
  float mean = ps * (1.f / 128.f);
  float var  = pq * (1.f / 128.f) - mean * mean;
  float rstd = rsqrtf(var + 1e-5f);
  f32x4 l4 = (x4 - mean) * rstd * (*(const f32x4*)(lnsg + jq)) + (*(const f32x4*)(lnsb + jq));
  *(f32x4*)(lnq + t * 4) = l4;
  __syncthreads();
  f32x4 qa = {0.f, 0.f, 0.f, 0.f};
  const float* wqp = Wq + jq;
  const float* qrow = lnq + s * 128;
  for (int c = 0; c < 128; ++c)
    qa += *(const f32x4*)(wqp + c * 128) * qrow[c];
  qa *= 0.08838834764831845f;  // 1/sqrt(128)
  ushort4 uq = {f2bf(qa[0]), f2bf(qa[1]), f2bf(qa[2]), f2bf(qa[3])};
  *(ushort4*)(qout + b * 2048 + t * 4) = uq;
}

// ---- K2: fused dots -> softmax(S) -> (+EPS) -> per-wave num/den partials ----
__global__ __launch_bounds__(256) void k2_attn(
    const unsigned short* __restrict__ kmat, const unsigned short* __restrict__ vT,
    const unsigned short* __restrict__ qm,
    float* __restrict__ nump, float* __restrict__ denp) {
  const int nb = blockIdx.x, b = blockIdx.y;
  const int t = threadIdx.x, w = t >> 6, l = t & 63, lr = l & 15, lg = l >> 4;
  __shared__ __align__(16) unsigned short pbuf[4][512];  // per-wave p tile [16s][32n], swizzled

  const unsigned short* kb_ = kmat + (long)b * (NTOT * CDIM);
  const unsigned short* vb  = vT + (long)b * (CDIM * (long)NTOT);
  const unsigned short* qb  = qm + b * (16 * CDIM);

  short8 qf[4];
  #pragma unroll
  for (int kk = 0; kk < 4; ++kk)
    qf[kk] = *(const short8*)(qb + lr * CDIM + kk * 32 + lg * 8);

  f32x4 acc[8];
  #pragma unroll
  for (int i = 0; i < 8; ++i) acc[i] = (f32x4){0.f, 0.f, 0.f, 0.f};
  float den0 = 0.f, den1 = 0.f, den2 = 0.f, den3 = 0.f;

  char* pw = (char*)&pbuf[w][0];

  #pragma unroll
  for (int it = 0; it < 4; ++it) {
    const int n0 = nb * 512 + (it * 4 + w) * 32;
    #pragma unroll
    for (int half = 0; half < 2; ++half) {
      f32x4 d = {0.f, 0.f, 0.f, 0.f};
      const unsigned short* krow = kb_ + (n0 + half * 16 + lr) * CDIM + lg * 8;
      #pragma unroll
      for (int kk = 0; kk < 4; ++kk) {
        short8 kf = *(const short8*)(krow + kk * 32);
        d = __builtin_amdgcn_mfma_f32_16x16x32_bf16(qf[kk], kf, d, 0, 0, 0);
      }
      // softmax over s (16 rows of D, spread over 4 regs x 4 lane-groups)
      float e0 = __expf(d[0]), e1 = __expf(d[1]), e2 = __expf(d[2]), e3 = __expf(d[3]);
      float cs = e0 + e1 + e2 + e3;
      cs += __shfl_xor(cs, 16);
      cs += __shfl_xor(cs, 32);
      float inv = 1.f / cs;
      float p0 = e0 * inv + 1e-8f, p1 = e1 * inv + 1e-8f,
            p2 = e2 * inv + 1e-8f, p3 = e3 * inv + 1e-8f;
      den0 += p0; den1 += p1; den2 += p2; den3 += p3;
      unsigned short pv0 = f2bf(p0), pv1 = f2bf(p1), pv2 = f2bf(p2), pv3 = f2bf(p3);
      int nn = half * 16 + lr;
      int s0 = lg * 4;
      unsigned ba0 = ((unsigned)((s0+0) * 64 + nn * 2)) ^ (((unsigned)(s0+0) & 3u) << 4);
      unsigned ba1 = ((unsigned)((s0+1) * 64 + nn * 2)) ^ (((unsigned)(s0+1) & 3u) << 4);
      unsigned ba2 = ((unsigned)((s0+2) * 64 + nn * 2)) ^ (((unsigned)(s0+2) & 3u) << 4);
      unsigned ba3 = ((unsigned)((s0+3) * 64 + nn * 2)) ^ (((unsigned)(s0+3) & 3u) << 4);
      *(unsigned short*)(pw + ba0) = pv0;
      *(unsigned short*)(pw + ba1) = pv1;
      *(unsigned short*)(pw + ba2) = pv2;
      *(unsigned short*)(pw + ba3) = pv3;
    }
    asm volatile("" ::: "memory");  // same-wave LDS RAW: DS ops are in-order; fence the compiler
    short8 pf;
    {
      unsigned ba = ((unsigned)(lr * 64 + lg * 16)) ^ (((unsigned)lr & 3u) << 4);
      pf = *(const short8*)(pw + ba);
    }
    // numT[c][s] += vT-frag * p-frag over K=32 n's
    #pragma unroll
    for (int ct = 0; ct < 8; ++ct) {
      const unsigned short* vrow = vb + (ct * 16 + lr) * NTOT + n0 + lg * 8;
      short8 vf = *(const short8*)vrow;
      acc[ct] = __builtin_amdgcn_mfma_f32_16x16x32_bf16(vf, pf, acc[ct], 0, 0, 0);
    }
    asm volatile("" ::: "memory");
  }

  // per-wave partial straight to global: nump[b][nb][w][s][c]
  float* outp = nump + (((long)b * 32 + nb) * 4 + w) * 2048;
  #pragma unroll
  for (int ct = 0; ct < 8; ++ct)
    *(f32x4*)(outp + lr * 128 + ct * 16 + lg * 4) = acc[ct];

  den0 += __shfl_xor(den0, 1); den0 += __shfl_xor(den0, 2); den0 += __shfl_xor(den0, 4); den0 += __shfl_xor(den0, 8);
  den1 += __shfl_xor(den1, 1); den1 += __shfl_xor(den1, 2); den1 += __shfl_xor(den1, 4); den1 += __shfl_xor(den1, 8);
  den2 += __shfl_xor(den2, 1); den2 += __shfl_xor(den2, 2); den2 += __shfl_xor(den2, 4); den2 += __shfl_xor(den2, 8);
  den3 += __shfl_xor(den3, 1); den3 += __shfl_xor(den3, 2); den3 += __shfl_xor(den3, 4); den3 += __shfl_xor(den3, 8);
  if (lr == 0) {
    float* dp = denp + (((long)b * 32 + nb) * 4 + w) * 16 + lg * 4;
    dp[0] = den0; dp[1] = den1; dp[2] = den2; dp[3] = den3;
  }
}

// ---- KR: reduce per-wave partials -> updates[b][s][c] (den division folded) ----
__global__ __launch_bounds__(128) void kr_reduce(const float* __restrict__ nump,
    const float* __restrict__ denp, float* __restrict__ upd) {
  const int bs = blockIdx.x;  // b*16 + s
  const int b = bs >> 4, s = bs & 15, t = threadIdx.x;
  __shared__ float dpart[2];
  float d = denp[((long)b * 128 + t) * 16 + s];
  d += __shfl_xor(d, 1); d += __shfl_xor(d, 2); d += __shfl_xor(d, 4);
  d += __shfl_xor(d, 8); d += __shfl_xor(d, 16); d += __shfl_xor(d, 32);
  if ((t & 63) == 0) dpart[t >> 6] = d;
  __syncthreads();
  float dtot = dpart[0] + dpart[1];
  float ns = 0.f;
  const float* np = nump + (long)b * 262144 + s * 128 + t;
  #pragma unroll 4
  for (int p = 0; p < 128; ++p) ns += np[(long)p * 2048];
  upd[b * 2048 + s * 128 + t] = ns / dtot;
}

// ---- K3: updates -> GRU -> MLP -> slots_out (+ q next) ----
__global__ __launch_bounds__(512) void k3_update(
    const float* __restrict__ sprev, const float* __restrict__ upd_g,
    const float* __restrict__ wih, const float* __restrict__ whh,
    const float* __restrict__ bih, const float* __restrict__ bhh,
    const float* __restrict__ w1, const float* __restrict__ b1,
    const float* __restrict__ w2, const float* __restrict__ b2,
    const float* __restrict__ lnfg, const float* __restrict__ lnfb,
    const float* __restrict__ lnsg, const float* __restrict__ lnsb,
    const float* __restrict__ Wq,
    float* __restrict__ sout, unsigned short* __restrict__ qout, const int doq) {
  const int b = blockIdx.x, t = threadIdx.x;
  const int s = t >> 5, jq = (t & 31) * 4;
  __shared__ __align__(16) float sp[2048];
  __shared__ __align__(16) float upd[2048];
  __shared__ __align__(16) float lnb[2048];

  f32x4 hp4 = *(const f32x4*)(sprev + b * 2048 + t * 4);
  *(f32x4*)(sp + t * 4) = hp4;
  f32x4 u4 = *(const f32x4*)(upd_g + b * 2048 + t * 4);
  *(f32x4*)(upd + t * 4) = u4;
  __syncthreads();

  // GRU: gi = upd@wih + bih ; gh = sp@whh + bhh ; gates r,z,n
  f32x4 ir = {0,0,0,0}, iz = {0,0,0,0}, inn = {0,0,0,0};
  f32x4 hr = {0,0,0,0}, hz = {0,0,0,0}, hn = {0,0,0,0};
  const float* wih_p = wih + jq;
  const float* whh_p = whh + jq;
  const float* ur  = upd + s * 128;
  const float* hrw = sp + s * 128;
  for (int c = 0; c < 128; ++c) {
    float u = ur[c], h = hrw[c];
    ir  += *(const f32x4*)(wih_p + c * 384)       * u;
    iz  += *(const f32x4*)(wih_p + c * 384 + 128) * u;
    inn += *(const f32x4*)(wih_p + c * 384 + 256) * u;
    hr  += *(const f32x4*)(whh_p + c * 384)       * h;
    hz  += *(const f32x4*)(whh_p + c * 384 + 128) * h;
    hn  += *(const f32x4*)(whh_p + c * 384 + 256) * h;
  }
  ir  += *(const f32x4*)(bih + jq);
  iz  += *(const f32x4*)(bih + 128 + jq);
  inn += *(const f32x4*)(bih + 256 + jq);
  hr  += *(const f32x4*)(bhh + jq);
  hz  += *(const f32x4*)(bhh + 128 + jq);
  hn  += *(const f32x4*)(bhh + 256 + jq);
  f32x4 snew;
  #pragma unroll
  for (int i = 0; i < 4; ++i) {
    float r = sigf(ir[i] + hr[i]);
    float z = sigf(iz[i] + hz[i]);
    float n = tanhfast(inn[i] + r * hn[i]);
    snew[i] = (1.f - z) * n + z * hp4[i];
  }

  // ln_ff stats via shfl over the 32 threads of this row
  float ps = snew[0] + snew[1] + snew[2] + snew[3];
  float pq = snew[0]*snew[0] + snew[1]*snew[1] + snew[2]*snew[2] + snew[3]*snew[3];
  ps += __shfl_xor(ps, 1); ps += __shfl_xor(ps, 2); ps += __shfl_xor(ps, 4); ps += __shfl_xor(ps, 8); ps += __shfl_xor(ps, 16);
  pq += __shfl_xor(pq, 1); pq += __shfl_xor(pq, 2); pq += __shfl_xor(pq, 4); pq += __shfl_xor(pq, 8); pq += __shfl_xor(pq, 16);
  float mean = ps * (1.f / 128.f);
  float var  = pq * (1.f / 128.f) - mean * mean;
  float rstd = rsqrtf(var + 1e-5f);
  f32x4 lf = (snew - mean) * rstd * (*(const f32x4*)(lnfg + jq)) + (*(const f32x4*)(lnfb + jq));
  *(f32x4*)(lnb + t * 4) = lf;
  __syncthreads();

  // MLP layer 1 + ReLU
  f32x4 ha = {0,0,0,0};
  const float* w1p = w1 + jq;
  const float* lrow = lnb + s * 128;
  for (int c = 0; c < 128; ++c)
    ha += *(const f32x4*)(w1p + c * 128) * lrow[c];
  ha += *(const f32x4*)(b1 + jq);
  #pragma unroll
  for (int i = 0; i < 4; ++i) ha[i] = fmaxf(ha[i], 0.f);
  *(f32x4*)(upd + t * 4) = ha;   // safe: all GRU reads of upd finished before lnb barrier
  __syncthreads();

  // MLP layer 2 + residual
  f32x4 oa = {0,0,0,0};
  const float* w2p = w2 + jq;
  const float* hrow = upd + s * 128;
  for (int c = 0; c < 128; ++c)
    oa += *(const f32x4*)(w2p + c * 128) * hrow[c];
  oa += *(const f32x4*)(b2 + jq);
  f32x4 sf = snew + oa;
  *(f32x4*)(sout + b * 2048 + t * 4) = sf;

  if (doq) {
    float qs = sf[0] + sf[1] + sf[2] + sf[3];
    float qz = sf[0]*sf[0] + sf[1]*sf[1] + sf[2]*sf[2] + sf[3]*sf[3];
    qs += __shfl_xor(qs, 1); qs += __shfl_xor(qs, 2); qs += __shfl_xor(qs, 4); qs += __shfl_xor(qs, 8); qs += __shfl_xor(qs, 16);
    qz += __shfl_xor(qz, 1); qz += __shfl_xor(qz, 2); qz += __shfl_xor(qz, 4); qz += __shfl_xor(qz, 8); qz += __shfl_xor(qz, 16);
    float m2 = qs * (1.f / 128.f);
    float v2 = qz * (1.f / 128.f) - m2 * m2;
    float rs2 = rsqrtf(v2 + 1e-5f);
    f32x4 lq = (sf - m2) * rs2 * (*(const f32x4*)(lnsg + jq)) + (*(const f32x4*)(lnsb + jq));
    *(f32x4*)(sp + t * 4) = lq;   // reuse sp
    __syncthreads();
    f32x4 qa = {0,0,0,0};
    const float* wqp = Wq + jq;
    const float* qrow = sp + s * 128;
    for (int c = 0; c < 128; ++c)
      qa += *(const f32x4*)(wqp + c * 128) * qrow[c];
    qa *= 0.08838834764831845f;
    ushort4 uq = {f2bf(qa[0]), f2bf(qa[1]), f2bf(qa[2]), f2bf(qa[3])};
    *(ushort4*)(qout + b * 2048 + t * 4) = uq;
  }
}

extern "C" void kernel_launch(void* const* d_in, const int* in_sizes, int n_in,
                              void* d_out, int out_size, void* d_ws, size_t ws_size,
                              hipStream_t stream) {
  (void)in_sizes; (void)n_in; (void)out_size; (void)ws_size;
  const float* slots = (const float*)d_in[0];
  const float* inputs = (const float*)d_in[1];
  const float* Wq  = (const float*)d_in[2];
  const float* Wk  = (const float*)d_in[3];
  const float* Wv  = (const float*)d_in[4];
  const float* wih = (const float*)d_in[5];
  const float* whh = (const float*)d_in[6];
  const float* bih = (const float*)d_in[7];
  const float* bhh = (const float*)d_in[8];
  const float* w1  = (const float*)d_in[9];
  const float* b1  = (const float*)d_in[10];
  const float* w2  = (const float*)d_in[11];
  const float* b2  = (const float*)d_in[12];
  const float* lnig = (const float*)d_in[13];
  const float* lnib = (const float*)d_in[14];
  const float* lnsg = (const float*)d_in[15];
  const float* lnsb = (const float*)d_in[16];
  const float* lnfg = (const float*)d_in[17];
  const float* lnfb = (const float*)d_in[18];

  char* ws = (char*)d_ws;
  unsigned short* kmat = (unsigned short*)(ws);
  unsigned short* vT   = (unsigned short*)(ws + 134217728L);
  unsigned short* qbuf = (unsigned short*)(ws + 268435456L);
  unsigned short* wpk  = (unsigned short*)(ws + 268566528L);
  float* nump = (float*)(ws + 268632064L);
  float* denp = (float*)(ws + 302186496L);
  float* upd  = (float*)(ws + 302710784L);
  float* sbuf = (float*)(ws + 302972928L);

  k0_prep<<<128, 256, 0, stream>>>(Wk, Wv, wpk);
  k1_lnkv<<<8192, 256, 0, stream>>>(inputs, lnig, lnib, wpk, kmat, vT);
  kq_init<<<32, 512, 0, stream>>>(slots, lnsg, lnsb, Wq, qbuf);
  for (int it = 0; it < 3; ++it) {
    k2_attn<<<dim3(32, 32), 256, 0, stream>>>(kmat, vT, qbuf, nump, denp);
    kr_reduce<<<512, 128, 0, stream>>>(nump, denp, upd);
    const float* sprev = (it == 0) ? slots : sbuf;
    float* sdst = (it == 2) ? (float*)d_out : sbuf;
    k3_update<<<32, 512, 0, stream>>>(sprev, upd, wih, whh, bih, bhh,
                                      w1, b1, w2, b2, lnfg, lnfb, lnsg, lnsb, Wq,
                                      sdst, qbuf, (it < 2) ? 1 : 0);
  }
}

// Round 3
// 605.628 us; speedup vs baseline: 1.1127x; 1.1127x over previous
//
#include <hip/hip_runtime.h>

// SlotAttention MI355X implementation, v3.
// k0: pre-pack Wk|Wv into MFMA B-fragment lane order (bf16, L2-resident).
// k1: barrier-free LN+project: each wave LNs its own 16 rows into its own LDS
//     slice and MFMAs them against prepacked weights -> k[b][n][c], vT[b][c][n].
// kq: q from initial slots. Then 3x { k2: fused dots/softmax/renorm partial
// accumulate (2048 blocks, in-block pair reduction); kr: reduce partials ->
// updates; k3: GRU + MLP -> new slots (+ q for next iter) }.
// Workspace (~289 MiB):
//   kmat  bf16 [32][16384][128]      @ 0
//   vT    bf16 [32][128][16384]      @ 134217728
//   qbuf  bf16 [32][16][128]         @ 268435456
//   wpk   bf16 [2][8][4][64][8]      @ 268566528
//   nump  f32  [32][64][2][16][128]  @ 268632064   (33.5 MB)
//   denp  f32  [32][64][2][16]       @ 302186496
//   upd   f32  [32][16][128]         @ 302448640
//   sbuf  f32  [32][16][128]         @ 302710784

#define NTOT 16384
#define CDIM 128

using short8 = __attribute__((ext_vector_type(8))) short;
using f32x4  = __attribute__((ext_vector_type(4))) float;

__device__ __forceinline__ unsigned short f2bf(float x) {
  union { float f; unsigned u; } v; v.f = x;
  unsigned r = v.u + 0x7FFFu + ((v.u >> 16) & 1u);
  return (unsigned short)(r >> 16);
}
__device__ __forceinline__ float sigf(float x) { return 1.f / (1.f + __expf(-x)); }
__device__ __forceinline__ float tanhfast(float x) {
  x = fminf(fmaxf(x, -15.f), 15.f);
  float e = __expf(2.f * x);
  return (e - 1.f) / (e + 1.f);
}

// ---- K0: pre-pack weights into B-fragment lane order ----
// wpk[which][ct][kb][lane][j] = W[c_in = kb*32 + (lane>>4)*8 + j][c_out = ct*16 + (lane&15)]
__global__ __launch_bounds__(256) void k0_prep(const float* __restrict__ Wk,
    const float* __restrict__ Wv, unsigned short* __restrict__ wpk) {
  int idx = blockIdx.x * 256 + threadIdx.x;  // 0..32767
  int j = idx & 7, lane = (idx >> 3) & 63, kb = (idx >> 9) & 3,
      ct = (idx >> 11) & 7, which = idx >> 14;
  int lr = lane & 15, lg = lane >> 4;
  int cin = kb * 32 + lg * 8 + j, cout = ct * 16 + lr;
  const float* W = which ? Wv : Wk;
  wpk[idx] = f2bf(W[cin * 128 + cout]);
}

// ---- K1: barrier-free LN(inputs) -> k, vT (per-wave self-contained) ----
__global__ __launch_bounds__(256) void k1_lnkv(
    const float* __restrict__ in, const float* __restrict__ gam,
    const float* __restrict__ bet, const unsigned short* __restrict__ wpk,
    unsigned short* __restrict__ kmat, unsigned short* __restrict__ vT) {
  __shared__ __align__(16) unsigned short xln[8192];  // 16 KB, 4 KB per wave
  const int t = threadIdx.x, w = t >> 6, l = t & 63, lr = l & 15, lg = l >> 4;
  const long rowbase = (long)blockIdx.x * 64;
  unsigned short* xw = xln + w * 2048;  // this wave's slice (16 rows x 128 c)

  // LayerNorm: wave owns rows w*16..+15; lane: lr = row, lg = 32-elem chunk
  {
    const float* src = in + (rowbase + w * 16 + lr) * CDIM + lg * 32;
    float x[32];
    #pragma unroll
    for (int i = 0; i < 8; ++i) {
      float4 v4 = ((const float4*)src)[i];
      x[i*4+0] = v4.x; x[i*4+1] = v4.y; x[i*4+2] = v4.z; x[i*4+3] = v4.w;
    }
    float s1 = 0.f, s2 = 0.f;
    #pragma unroll
    for (int i = 0; i < 32; ++i) { s1 += x[i]; s2 += x[i] * x[i]; }
    s1 += __shfl_xor(s1, 16); s1 += __shfl_xor(s1, 32);
    s2 += __shfl_xor(s2, 16); s2 += __shfl_xor(s2, 32);
    float mean = s1 * (1.f / 128.f);
    float var  = s2 * (1.f / 128.f) - mean * mean;
    float rstd = rsqrtf(var + 1e-5f);
    #pragma unroll
    for (int j = 0; j < 4; ++j) {
      f32x4 g0 = *(const f32x4*)(gam + lg * 32 + j * 8);
      f32x4 g1 = *(const f32x4*)(gam + lg * 32 + j * 8 + 4);
      f32x4 b0 = *(const f32x4*)(bet + lg * 32 + j * 8);
      f32x4 b1 = *(const f32x4*)(bet + lg * 32 + j * 8 + 4);
      short8 yv;
      #pragma unroll
      for (int i = 0; i < 4; ++i) {
        yv[i]     = (short)f2bf((x[j*8+i]   - mean) * rstd * g0[i] + b0[i]);
        yv[i + 4] = (short)f2bf((x[j*8+4+i] - mean) * rstd * g1[i] + b1[i]);
      }
      // fragment-ordered: chunk (lg*4+j) of 8 elems, row lr
      *(short8*)((char*)xw + ((lg * 4 + j) * 16 + lr) * 16) = yv;
    }
  }
  asm volatile("" ::: "memory");  // same-wave LDS RAW: DS in-order; fence compiler

  short8 af[4];
  #pragma unroll
  for (int kb = 0; kb < 4; ++kb)
    af[kb] = *(const short8*)((const char*)xw + ((kb * 4 + lg) * 16 + lr) * 16);

  const long b = rowbase >> 14;
  // k pass: 8 col-tiles
  #pragma unroll
  for (int ct = 0; ct < 8; ++ct) {
    f32x4 a0 = {0.f, 0.f, 0.f, 0.f};
    #pragma unroll
    for (int kb = 0; kb < 4; ++kb) {
      short8 bf = *(const short8*)(wpk + ((ct * 4 + kb) * 64 + l) * 8);
      a0 = __builtin_amdgcn_mfma_f32_16x16x32_bf16(af[kb], bf, a0, 0, 0, 0);
    }
    #pragma unroll
    for (int r = 0; r < 4; ++r)
      kmat[(rowbase + w * 16 + lg * 4 + r) * CDIM + ct * 16 + lr] = f2bf(a0[r]);
  }
  // v pass (stored transposed: vT[b][c][n])
  unsigned short* vTb = vT + b * (CDIM * (long)NTOT);
  const long nloc = (rowbase & 16383) + w * 16 + lg * 4;
  #pragma unroll
  for (int ct = 0; ct < 8; ++ct) {
    f32x4 a0 = {0.f, 0.f, 0.f, 0.f};
    #pragma unroll
    for (int kb = 0; kb < 4; ++kb) {
      short8 bf = *(const short8*)(wpk + (((8 + ct) * 4 + kb) * 64 + l) * 8);
      a0 = __builtin_amdgcn_mfma_f32_16x16x32_bf16(af[kb], bf, a0, 0, 0, 0);
    }
    int c = ct * 16 + lr;
    ushort4 u0 = {f2bf(a0[0]), f2bf(a0[1]), f2bf(a0[2]), f2bf(a0[3])};
    *(ushort4*)(vTb + (long)c * NTOT + nloc) = u0;
  }
}

// ---- Kq: q = (LN_s(slots) @ Wq) / sqrt(C) -> bf16 (initial iteration) ----
__global__ __launch_bounds__(512) void kq_init(
    const float* __restrict__ slots, const float* __restrict__ lnsg,
    const float* __restrict__ lnsb, const float* __restrict__ Wq,
    unsigned short* __restrict__ qout) {
  const int b = blockIdx.x, t = threadIdx.x;
  const int s = t >> 5, jq = (t & 31) * 4;
  __shared__ __align__(16) float lnq[2048];
  f32x4 x4 = *(const f32x4*)(slots + b * 2048 + t * 4);
  float ps = x4[0] + x4[1] + x4[2] + x4[3];
  float pq = x4[0]*x4[0] + x4[1]*x4[1] + x4[2]*x4[2] + x4[3]*x4[3];
  ps += __shfl_xor(ps, 1); ps += __shfl_xor(ps, 2); ps += __shfl_xor(ps, 4); ps += __shfl_xor(ps, 8); ps += __shfl_xor(ps, 16);
  pq += __shfl_xor(pq, 1); pq += __shfl_xor(pq, 2); pq += __shfl_xor(pq, 4); pq += __shfl_xor(pq, 8); pq += __shfl_xor(pq, 16);
  float mean = ps * (1.f / 128.f);
  float var  = pq * (1.f / 128.f) - mean * mean;
  float rstd = rsqrtf(var + 1e-5f);
  f32x4 l4 = (x4 - mean) * rstd * (*(const f32x4*)(lnsg + jq)) + (*(const f32x4*)(lnsb + jq));
  *(f32x4*)(lnq + t * 4) = l4;
  __syncthreads();
  f32x4 qa = {0.f, 0.f, 0.f, 0.f};
  const float* wqp = Wq + jq;
  const float* qrow = lnq + s * 128;
  for (int c = 0; c < 128; ++c)
    qa += *(const f32x4*)(wqp + c * 128) * qrow[c];
  qa *= 0.08838834764831845f;  // 1/sqrt(128)
  ushort4 uq = {f2bf(qa[0]), f2bf(qa[1]), f2bf(qa[2]), f2bf(qa[3])};
  *(ushort4*)(qout + b * 2048 + t * 4) = uq;
}

// ---- K2: fused dots -> softmax(S) -> (+EPS) -> pair-reduced num/den partials ----
__global__ __launch_bounds__(256) void k2_attn(
    const unsigned short* __restrict__ kmat, const unsigned short* __restrict__ vT,
    const unsigned short* __restrict__ qm,
    float* __restrict__ nump, float* __restrict__ denp) {
  const int nb = blockIdx.x, b = blockIdx.y;
  const int t = threadIdx.x, w = t >> 6, l = t & 63, lr = l & 15, lg = l >> 4;
  __shared__ __align__(16) unsigned short pbuf[4][512];  // per-wave p tile
  __shared__ __align__(16) float redbuf[2][2048];        // waves 2,3 partials
  __shared__ float denbuf[2][16];

  const unsigned short* kb_ = kmat + (long)b * (NTOT * CDIM);
  const unsigned short* vb  = vT + (long)b * (CDIM * (long)NTOT);
  const unsigned short* qb  = qm + b * (16 * CDIM);

  short8 qf[4];
  #pragma unroll
  for (int kk = 0; kk < 4; ++kk)
    qf[kk] = *(const short8*)(qb + lr * CDIM + kk * 32 + lg * 8);

  f32x4 acc[8];
  #pragma unroll
  for (int i = 0; i < 8; ++i) acc[i] = (f32x4){0.f, 0.f, 0.f, 0.f};
  float den0 = 0.f, den1 = 0.f, den2 = 0.f, den3 = 0.f;

  char* pw = (char*)&pbuf[w][0];

  #pragma unroll
  for (int it = 0; it < 2; ++it) {
    const int n0 = nb * 256 + (it * 4 + w) * 32;
    #pragma unroll
    for (int half = 0; half < 2; ++half) {
      f32x4 d = {0.f, 0.f, 0.f, 0.f};
      const unsigned short* krow = kb_ + (n0 + half * 16 + lr) * CDIM + lg * 8;
      #pragma unroll
      for (int kk = 0; kk < 4; ++kk) {
        short8 kf = *(const short8*)(krow + kk * 32);
        d = __builtin_amdgcn_mfma_f32_16x16x32_bf16(qf[kk], kf, d, 0, 0, 0);
      }
      // softmax over s (16 rows of D, spread over 4 regs x 4 lane-groups)
      float e0 = __expf(d[0]), e1 = __expf(d[1]), e2 = __expf(d[2]), e3 = __expf(d[3]);
      float cs = e0 + e1 + e2 + e3;
      cs += __shfl_xor(cs, 16);
      cs += __shfl_xor(cs, 32);
      float inv = 1.f / cs;
      float p0 = e0 * inv + 1e-8f, p1 = e1 * inv + 1e-8f,
            p2 = e2 * inv + 1e-8f, p3 = e3 * inv + 1e-8f;
      den0 += p0; den1 += p1; den2 += p2; den3 += p3;
      unsigned short pv0 = f2bf(p0), pv1 = f2bf(p1), pv2 = f2bf(p2), pv3 = f2bf(p3);
      int nn = half * 16 + lr;
      int s0 = lg * 4;
      unsigned ba0 = ((unsigned)((s0+0) * 64 + nn * 2)) ^ (((unsigned)(s0+0) & 3u) << 4);
      unsigned ba1 = ((unsigned)((s0+1) * 64 + nn * 2)) ^ (((unsigned)(s0+1) & 3u) << 4);
      unsigned ba2 = ((unsigned)((s0+2) * 64 + nn * 2)) ^ (((unsigned)(s0+2) & 3u) << 4);
      unsigned ba3 = ((unsigned)((s0+3) * 64 + nn * 2)) ^ (((unsigned)(s0+3) & 3u) << 4);
      *(unsigned short*)(pw + ba0) = pv0;
      *(unsigned short*)(pw + ba1) = pv1;
      *(unsigned short*)(pw + ba2) = pv2;
      *(unsigned short*)(pw + ba3) = pv3;
    }
    asm volatile("" ::: "memory");  // same-wave LDS RAW ordering fence
    short8 pf;
    {
      unsigned ba = ((unsigned)(lr * 64 + lg * 16)) ^ (((unsigned)lr & 3u) << 4);
      pf = *(const short8*)(pw + ba);
    }
    // numT[c][s] += vT-frag * p-frag over K=32 n's
    #pragma unroll
    for (int ct = 0; ct < 8; ++ct) {
      const unsigned short* vrow = vb + (ct * 16 + lr) * NTOT + n0 + lg * 8;
      short8 vf = *(const short8*)vrow;
      acc[ct] = __builtin_amdgcn_mfma_f32_16x16x32_bf16(vf, pf, acc[ct], 0, 0, 0);
    }
    asm volatile("" ::: "memory");
  }

  // den: reduce over lr within lane-groups (each lg group holds 4 s-rows)
  den0 += __shfl_xor(den0, 1); den0 += __shfl_xor(den0, 2); den0 += __shfl_xor(den0, 4); den0 += __shfl_xor(den0, 8);
  den1 += __shfl_xor(den1, 1); den1 += __shfl_xor(den1, 2); den1 += __shfl_xor(den1, 4); den1 += __shfl_xor(den1, 8);
  den2 += __shfl_xor(den2, 1); den2 += __shfl_xor(den2, 2); den2 += __shfl_xor(den2, 4); den2 += __shfl_xor(den2, 8);
  den3 += __shfl_xor(den3, 1); den3 += __shfl_xor(den3, 2); den3 += __shfl_xor(den3, 4); den3 += __shfl_xor(den3, 8);

  // waves 2,3 park partials in LDS; waves 0,1 fold and write to global
  if (w >= 2) {
    float* rw_ = &redbuf[w - 2][0];
    #pragma unroll
    for (int ct = 0; ct < 8; ++ct)
      *(f32x4*)(rw_ + lr * 128 + ct * 16 + lg * 4) = acc[ct];
    if (lr == 0) {
      denbuf[w - 2][lg * 4 + 0] = den0;
      denbuf[w - 2][lg * 4 + 1] = den1;
      denbuf[w - 2][lg * 4 + 2] = den2;
      denbuf[w - 2][lg * 4 + 3] = den3;
    }
  }
  __syncthreads();
  if (w < 2) {
    const float* rw_ = &redbuf[w][0];
    float* outp = nump + (((long)b * 64 + nb) * 2 + w) * 2048;
    #pragma unroll
    for (int ct = 0; ct < 8; ++ct) {
      f32x4 other = *(const f32x4*)(rw_ + lr * 128 + ct * 16 + lg * 4);
      *(f32x4*)(outp + lr * 128 + ct * 16 + lg * 4) = acc[ct] + other;
    }
    if (lr == 0) {
      float* dp = denp + (((long)b * 64 + nb) * 2 + w) * 16 + lg * 4;
      dp[0] = den0 + denbuf[w][lg * 4 + 0];
      dp[1] = den1 + denbuf[w][lg * 4 + 1];
      dp[2] = den2 + denbuf[w][lg * 4 + 2];
      dp[3] = den3 + denbuf[w][lg * 4 + 3];
    }
  }
}

// ---- KR: reduce per-wave partials -> updates[b][s][c] (den division folded) ----
__global__ __launch_bounds__(128) void kr_reduce(const float* __restrict__ nump,
    const float* __restrict__ denp, float* __restrict__ upd) {
  const int bs = blockIdx.x;  // b*16 + s
  const int b = bs >> 4, s = bs & 15, t = threadIdx.x;
  __shared__ float dpart[2];
  float d = denp[((long)b * 128 + t) * 16 + s];
  d += __shfl_xor(d, 1); d += __shfl_xor(d, 2); d += __shfl_xor(d, 4);
  d += __shfl_xor(d, 8); d += __shfl_xor(d, 16); d += __shfl_xor(d, 32);
  if ((t & 63) == 0) dpart[t >> 6] = d;
  __syncthreads();
  float dtot = dpart[0] + dpart[1];
  float ns = 0.f;
  const float* np = nump + (long)b * 262144 + s * 128 + t;
  #pragma unroll 4
  for (int p = 0; p < 128; ++p) ns += np[(long)p * 2048];
  upd[b * 2048 + s * 128 + t] = ns / dtot;
}

// ---- K3: updates -> GRU -> MLP -> slots_out (+ q next); block = (g,b), 4 s-rows ----
__global__ __launch_bounds__(128) void k3_update(
    const float* __restrict__ sprev, const float* __restrict__ upd_g,
    const float* __restrict__ wih, const float* __restrict__ whh,
    const float* __restrict__ bih, const float* __restrict__ bhh,
    const float* __restrict__ w1, const float* __restrict__ b1,
    const float* __restrict__ w2, const float* __restrict__ b2,
    const float* __restrict__ lnfg, const float* __restrict__ lnfb,
    const float* __restrict__ lnsg, const float* __restrict__ lnsb,
    const float* __restrict__ Wq,
    float* __restrict__ sout, unsigned short* __restrict__ qout, const int doq) {
  const int g = blockIdx.x, b = blockIdx.y, t = threadIdx.x;
  const int sl = t >> 5, jq = (t & 31) * 4;
  const long base = (long)b * 2048 + g * 512;
  __shared__ __align__(16) float sp[512];
  __shared__ __align__(16) float upd[512];
  __shared__ __align__(16) float lnb[512];

  f32x4 hp4 = *(const f32x4*)(sprev + base + t * 4);
  *(f32x4*)(sp + t * 4) = hp4;
  f32x4 u4 = *(const f32x4*)(upd_g + base + t * 4);
  *(f32x4*)(upd + t * 4) = u4;
  __syncthreads();

  // GRU: gi = upd@wih + bih ; gh = sp@whh + bhh ; gates r,z,n
  f32x4 ir = {0,0,0,0}, iz = {0,0,0,0}, inn = {0,0,0,0};
  f32x4 hr = {0,0,0,0}, hz = {0,0,0,0}, hn = {0,0,0,0};
  const float* wih_p = wih + jq;
  const float* whh_p = whh + jq;
  const float* ur  = upd + sl * 128;
  const float* hrw = sp + sl * 128;
  for (int c = 0; c < 128; ++c) {
    float u = ur[c], h = hrw[c];
    ir  += *(const f32x4*)(wih_p + c * 384)       * u;
    iz  += *(const f32x4*)(wih_p + c * 384 + 128) * u;
    inn += *(const f32x4*)(wih_p + c * 384 + 256) * u;
    hr  += *(const f32x4*)(whh_p + c * 384)       * h;
    hz  += *(const f32x4*)(whh_p + c * 384 + 128) * h;
    hn  += *(const f32x4*)(whh_p + c * 384 + 256) * h;
  }
  ir  += *(const f32x4*)(bih + jq);
  iz  += *(const f32x4*)(bih + 128 + jq);
  inn += *(const f32x4*)(bih + 256 + jq);
  hr  += *(const f32x4*)(bhh + jq);
  hz  += *(const f32x4*)(bhh + 128 + jq);
  hn  += *(const f32x4*)(bhh + 256 + jq);
  f32x4 snew;
  #pragma unroll
  for (int i = 0; i < 4; ++i) {
    float r = sigf(ir[i] + hr[i]);
    float z = sigf(iz[i] + hz[i]);
    float n = tanhfast(inn[i] + r * hn[i]);
    snew[i] = (1.f - z) * n + z * hp4[i];
  }

  // ln_ff stats via shfl over the 32 threads of this row
  float ps = snew[0] + snew[1] + snew[2] + snew[3];
  float pq = snew[0]*snew[0] + snew[1]*snew[1] + snew[2]*snew[2] + snew[3]*snew[3];
  ps += __shfl_xor(ps, 1); ps += __shfl_xor(ps, 2); ps += __shfl_xor(ps, 4); ps += __shfl_xor(ps, 8); ps += __shfl_xor(ps, 16);
  pq += __shfl_xor(pq, 1); pq += __shfl_xor(pq, 2); pq += __shfl_xor(pq, 4); pq += __shfl_xor(pq, 8); pq += __shfl_xor(pq, 16);
  float mean = ps * (1.f / 128.f);
  float var  = pq * (1.f / 128.f) - mean * mean;
  float rstd = rsqrtf(var + 1e-5f);
  f32x4 lf = (snew - mean) * rstd * (*(const f32x4*)(lnfg + jq)) + (*(const f32x4*)(lnfb + jq));
  *(f32x4*)(lnb + t * 4) = lf;
  __syncthreads();

  // MLP layer 1 + ReLU
  f32x4 ha = {0,0,0,0};
  const float* w1p = w1 + jq;
  const float* lrow = lnb + sl * 128;
  for (int c = 0; c < 128; ++c)
    ha += *(const f32x4*)(w1p + c * 128) * lrow[c];
  ha += *(const f32x4*)(b1 + jq);
  #pragma unroll
  for (int i = 0; i < 4; ++i) ha[i] = fmaxf(ha[i], 0.f);
  *(f32x4*)(upd + t * 4) = ha;
  __syncthreads();

  // MLP layer 2 + residual
  f32x4 oa = {0,0,0,0};
  const float* w2p = w2 + jq;
  const float* hrow = upd + sl * 128;
  for (int c = 0; c < 128; ++c)
    oa += *(const f32x4*)(w2p + c * 128) * hrow[c];
  oa += *(const f32x4*)(b2 + jq);
  f32x4 sf = snew + oa;
  *(f32x4*)(sout + base + t * 4) = sf;

  if (doq) {
    float qs = sf[0] + sf[1] + sf[2] + sf[3];
    float qz = sf[0]*sf[0] + sf[1]*sf[1] + sf[2]*sf[2] + sf[3]*sf[3];
    qs += __shfl_xor(qs, 1); qs += __shfl_xor(qs, 2); qs += __shfl_xor(qs, 4); qs += __shfl_xor(qs, 8); qs += __shfl_xor(qs, 16);
    qz += __shfl_xor(qz, 1); qz += __shfl_xor(qz, 2); qz += __shfl_xor(qz, 4); qz += __shfl_xor(qz, 8); qz += __shfl_xor(qz, 16);
    float m2 = qs * (1.f / 128.f);
    float v2 = qz * (1.f / 128.f) - m2 * m2;
    float rs2 = rsqrtf(v2 + 1e-5f);
    f32x4 lq = (sf - m2) * rs2 * (*(const f32x4*)(lnsg + jq)) + (*(const f32x4*)(lnsb + jq));
    *(f32x4*)(sp + t * 4) = lq;   // reuse sp
    __syncthreads();
    f32x4 qa = {0,0,0,0};
    const float* wqp = Wq + jq;
    const float* qrow = sp + sl * 128;
    for (int c = 0; c < 128; ++c)
      qa += *(const f32x4*)(wqp + c * 128) * qrow[c];
    qa *= 0.08838834764831845f;
    ushort4 uq = {f2bf(qa[0]), f2bf(qa[1]), f2bf(qa[2]), f2bf(qa[3])};
    *(ushort4*)(qout + base + t * 4) = uq;
  }
}

extern "C" void kernel_launch(void* const* d_in, const int* in_sizes, int n_in,
                              void* d_out, int out_size, void* d_ws, size_t ws_size,
                              hipStream_t stream) {
  (void)in_sizes; (void)n_in; (void)out_size; (void)ws_size;
  const float* slots = (const float*)d_in[0];
  const float* inputs = (const float*)d_in[1];
  const float* Wq  = (const float*)d_in[2];
  const float* Wk  = (const float*)d_in[3];
  const float* Wv  = (const float*)d_in[4];
  const float* wih = (const float*)d_in[5];
  const float* whh = (const float*)d_in[6];
  const float* bih = (const float*)d_in[7];
  const float* bhh = (const float*)d_in[8];
  const float* w1  = (const float*)d_in[9];
  const float* b1  = (const float*)d_in[10];
  const float* w2  = (const float*)d_in[11];
  const float* b2  = (const float*)d_in[12];
  const float* lnig = (const float*)d_in[13];
  const float* lnib = (const float*)d_in[14];
  const float* lnsg = (const float*)d_in[15];
  const float* lnsb = (const float*)d_in[16];
  const float* lnfg = (const float*)d_in[17];
  const float* lnfb = (const float*)d_in[18];

  char* ws = (char*)d_ws;
  unsigned short* kmat = (unsigned short*)(ws);
  unsigned short* vT   = (unsigned short*)(ws + 134217728L);
  unsigned short* qbuf = (unsigned short*)(ws + 268435456L);
  unsigned short* wpk  = (unsigned short*)(ws + 268566528L);
  float* nump = (float*)(ws + 268632064L);
  float* denp = (float*)(ws + 302186496L);
  float* upd  = (float*)(ws + 302448640L);
  float* sbuf = (float*)(ws + 302710784L);

  k0_prep<<<128, 256, 0, stream>>>(Wk, Wv, wpk);
  k1_lnkv<<<8192, 256, 0, stream>>>(inputs, lnig, lnib, wpk, kmat, vT);
  kq_init<<<32, 512, 0, stream>>>(slots, lnsg, lnsb, Wq, qbuf);
  for (int it = 0; it < 3; ++it) {
    k2_attn<<<dim3(64, 32), 256, 0, stream>>>(kmat, vT, qbuf, nump, denp);
    kr_reduce<<<512, 128, 0, stream>>>(nump, denp, upd);
    const float* sprev = (it == 0) ? slots : sbuf;
    float* sdst = (it == 2) ? (float*)d_out : sbuf;
    k3_update<<<dim3(4, 32), 128, 0, stream>>>(sprev, upd, wih, whh, bih, bhh,
                                      w1, b1, w2, b2, lnfg, lnfb, lnsg, lnsb, Wq,
                                      sdst, qbuf, (it < 2) ? 1 : 0);
  }
}

// Round 4
// 590.055 us; speedup vs baseline: 1.1421x; 1.0264x over previous
//
#include <hip/hip_runtime.h>

// SlotAttention MI355X implementation, v4.
// k0: pre-pack Wk|Wv into MFMA fragment lane order (bf16, L2-resident).
// k1: coalesced-load LN + operand-swapped MFMA -> k[b][n][c] (8B packed stores),
//     vT[b][c][n]. No block barrier (per-wave LDS slice only).
// kq: q from initial slots. Then 3x { k2: dots (swapped, D[n][s]) -> in-register
// softmax -> shfl-transpose -> PV MFMA, per-wave-pair partials to global;
// k3: reduce partials + den -> updates -> GRU -> MLP -> slots (+ q next) }.
// Workspace (~289 MiB):
//   kmat  bf16 [32][16384][128]      @ 0
//   vT    bf16 [32][128][16384]      @ 134217728
//   qbuf  bf16 [32][16][128]         @ 268435456
//   wpk   bf16 [2][8][4][64][8]      @ 268566528
//   nump  f32  [32][64][2][16][128]  @ 268632064   (33.5 MB)
//   denp  f32  [32][128][16]         @ 302186496
//   sbuf  f32  [32][16][128]         @ 302710784

#define NTOT 16384
#define CDIM 128

using short8 = __attribute__((ext_vector_type(8))) short;
using f32x4  = __attribute__((ext_vector_type(4))) float;
using u32x2  = __attribute__((ext_vector_type(2))) unsigned;

__device__ __forceinline__ unsigned pkbf(float lo, float hi) {
  unsigned r;
  asm("v_cvt_pk_bf16_f32 %0, %1, %2" : "=v"(r) : "v"(lo), "v"(hi));
  return r;
}
__device__ __forceinline__ unsigned short f2bf(float x) {
  union { float f; unsigned u; } v; v.f = x;
  unsigned r = v.u + 0x7FFFu + ((v.u >> 16) & 1u);
  return (unsigned short)(r >> 16);
}
__device__ __forceinline__ float sigf(float x) { return 1.f / (1.f + __expf(-x)); }
__device__ __forceinline__ float tanhfast(float x) {
  x = fminf(fmaxf(x, -15.f), 15.f);
  float e = __expf(2.f * x);
  return (e - 1.f) / (e + 1.f);
}

// ---- K0: pre-pack weights into MFMA fragment lane order ----
// wpk[which][ct][kb][lane][j] = W[cin = kb*32 + (lane>>4)*8 + j][cout = ct*16 + (lane&15)]
__global__ __launch_bounds__(256) void k0_prep(const float* __restrict__ Wk,
    const float* __restrict__ Wv, unsigned short* __restrict__ wpk) {
  int idx = blockIdx.x * 256 + threadIdx.x;  // 0..32767
  int j = idx & 7, lane = (idx >> 3) & 63, kb = (idx >> 9) & 3,
      ct = (idx >> 11) & 7, which = idx >> 14;
  int lr = lane & 15, lg = lane >> 4;
  int cin = kb * 32 + lg * 8 + j, cout = ct * 16 + lr;
  const float* W = which ? Wv : Wk;
  wpk[idx] = f2bf(W[cin * 128 + cout]);
}

// ---- K1: LN(inputs) -> k, vT. Coalesced loads, packed stores. ----
__global__ __launch_bounds__(256) void k1_lnkv(
    const float* __restrict__ in, const float* __restrict__ gam,
    const float* __restrict__ bet, const unsigned short* __restrict__ wpk,
    unsigned short* __restrict__ kmat, unsigned short* __restrict__ vT) {
  __shared__ __align__(16) unsigned short xln[8192];  // 16 KB, 4 KB per wave
  const int t = threadIdx.x, w = t >> 6, l = t & 63, lr = l & 15, lg = l >> 4;
  const long rowbase = (long)blockIdx.x * 64;
  char* xw = (char*)(xln + w * 2048);  // wave's 16 rows x 128 c, fragment-ordered

  // Coalesced load: lane l, instr i -> bytes [i*1024 + l*16); holds row 2i+(l>>5),
  // cols (l&31)*4..+3 of the wave's 16-row slab.
  const int lc = l & 31, lh = l >> 5;
  const float* src = in + (rowbase + w * 16) * CDIM;
  float x[8][4];
  #pragma unroll
  for (int i = 0; i < 8; ++i) {
    f32x4 v = *(const f32x4*)(src + i * 256 + l * 4);
    x[i][0] = v[0]; x[i][1] = v[1]; x[i][2] = v[2]; x[i][3] = v[3];
  }
  f32x4 g4 = *(const f32x4*)(gam + lc * 4);
  f32x4 b4 = *(const f32x4*)(bet + lc * 4);
  const int chunk = lc >> 1, sub = l & 1;
  #pragma unroll
  for (int i = 0; i < 8; ++i) {
    float s1 = x[i][0] + x[i][1] + x[i][2] + x[i][3];
    float s2 = x[i][0]*x[i][0] + x[i][1]*x[i][1] + x[i][2]*x[i][2] + x[i][3]*x[i][3];
    s1 += __shfl_xor(s1, 1); s1 += __shfl_xor(s1, 2); s1 += __shfl_xor(s1, 4);
    s1 += __shfl_xor(s1, 8); s1 += __shfl_xor(s1, 16);
    s2 += __shfl_xor(s2, 1); s2 += __shfl_xor(s2, 2); s2 += __shfl_xor(s2, 4);
    s2 += __shfl_xor(s2, 8); s2 += __shfl_xor(s2, 16);
    float mean = s1 * (1.f / 128.f);
    float var  = s2 * (1.f / 128.f) - mean * mean;
    float rstd = rsqrtf(var + 1e-5f);
    float y0 = (x[i][0] - mean) * rstd * g4[0] + b4[0];
    float y1 = (x[i][1] - mean) * rstd * g4[1] + b4[1];
    float y2 = (x[i][2] - mean) * rstd * g4[2] + b4[2];
    float y3 = (x[i][3] - mean) * rstd * g4[3] + b4[3];
    u32x2 pk = { pkbf(y0, y1), pkbf(y2, y3) };
    int row = 2 * i + lh;
    // fragment-ordered, XOR-swizzled: [chunk][row^chunk&7][16B], 8B sub-write
    unsigned addr = (unsigned)(chunk * 256 + ((row ^ (chunk & 7)) << 4) + sub * 8);
    *(u32x2*)(xw + addr) = pk;
  }
  asm volatile("" ::: "memory");  // same-wave LDS RAW: DS in-order; fence compiler

  short8 af[4];
  #pragma unroll
  for (int kb = 0; kb < 4; ++kb) {
    int ch = kb * 4 + lg;
    af[kb] = *(const short8*)(xw + ch * 256 + ((lr ^ (ch & 7)) << 4));
  }

  const long b = rowbase >> 14;
  // k pass, operand-swapped: D[cout][n] -> lane holds n=lr, c=ct*16+lg*4+r
  unsigned short* krow = kmat + (rowbase + w * 16 + lr) * CDIM;
  #pragma unroll
  for (int ct = 0; ct < 8; ++ct) {
    f32x4 a = {0.f, 0.f, 0.f, 0.f};
    #pragma unroll
    for (int kb = 0; kb < 4; ++kb) {
      short8 wf = *(const short8*)(wpk + ((ct * 4 + kb) * 64 + l) * 8);
      a = __builtin_amdgcn_mfma_f32_16x16x32_bf16(wf, af[kb], a, 0, 0, 0);
    }
    u32x2 pk = { pkbf(a[0], a[1]), pkbf(a[2], a[3]) };
    *(u32x2*)(krow + ct * 16 + lg * 4) = pk;
  }
  // v pass, unswapped: D[n][cout] -> lane holds c=ct*16+lr, n=base+lg*4+r
  unsigned short* vTb = vT + b * (CDIM * (long)NTOT);
  const long nloc = (rowbase & 16383) + w * 16 + lg * 4;
  #pragma unroll
  for (int ct = 0; ct < 8; ++ct) {
    f32x4 a = {0.f, 0.f, 0.f, 0.f};
    #pragma unroll
    for (int kb = 0; kb < 4; ++kb) {
      short8 wf = *(const short8*)(wpk + (((8 + ct) * 4 + kb) * 64 + l) * 8);
      a = __builtin_amdgcn_mfma_f32_16x16x32_bf16(af[kb], wf, a, 0, 0, 0);
    }
    int c = ct * 16 + lr;
    u32x2 pk = { pkbf(a[0], a[1]), pkbf(a[2], a[3]) };
    *(u32x2*)(vTb + (long)c * NTOT + nloc) = pk;
  }
}

// ---- Kq: q = (LN_s(slots) @ Wq) / sqrt(C) -> bf16 (initial iteration) ----
__global__ __launch_bounds__(512) void kq_init(
    const float* __restrict__ slots, const float* __restrict__ lnsg,
    const float* __restrict__ lnsb, const float* __restrict__ Wq,
    unsigned short* __restrict__ qout) {
  const int b = blockIdx.x, t = threadIdx.x;
  const int s = t >> 5, jq = (t & 31) * 4;
  __shared__ __align__(16) float lnq[2048];
  f32x4 x4 = *(const f32x4*)(slots + b * 2048 + t * 4);
  float ps = x4[0] + x4[1] + x4[2] + x4[3];
  float pq = x4[0]*x4[0] + x4[1]*x4[1] + x4[2]*x4[2] + x4[3]*x4[3];
  ps += __shfl_xor(ps, 1); ps += __shfl_xor(ps, 2); ps += __shfl_xor(ps, 4); ps += __shfl_xor(ps, 8); ps += __shfl_xor(ps, 16);
  pq += __shfl_xor(pq, 1); pq += __shfl_xor(pq, 2); pq += __shfl_xor(pq, 4); pq += __shfl_xor(pq, 8); pq += __shfl_xor(pq, 16);
  float mean = ps * (1.f / 128.f);
  float var  = pq * (1.f / 128.f) - mean * mean;
  float rstd = rsqrtf(var + 1e-5f);
  f32x4 l4 = (x4 - mean) * rstd * (*(const f32x4*)(lnsg + jq)) + (*(const f32x4*)(lnsb + jq));
  *(f32x4*)(lnq + t * 4) = l4;
  __syncthreads();
  f32x4 qa = {0.f, 0.f, 0.f, 0.f};
  const float* wqp = Wq + jq;
  const float* qrow = lnq + s * 128;
  for (int c = 0; c < 128; ++c)
    qa += *(const f32x4*)(wqp + c * 128) * qrow[c];
  qa *= 0.08838834764831845f;  // 1/sqrt(128)
  u32x2 pk = { pkbf(qa[0], qa[1]), pkbf(qa[2], qa[3]) };
  *(u32x2*)(qout + b * 2048 + t * 4) = pk;
}

// ---- K2: dots (swapped) -> in-register softmax -> shfl transpose -> PV ----
__global__ __launch_bounds__(256) void k2_attn(
    const unsigned short* __restrict__ kmat, const unsigned short* __restrict__ vT,
    const unsigned short* __restrict__ qm,
    float* __restrict__ nump, float* __restrict__ denp) {
  const int nb = blockIdx.x, b = blockIdx.y;
  const int t = threadIdx.x, w = t >> 6, l = t & 63, lr = l & 15, lg = l >> 4;
  __shared__ __align__(16) float redbuf[2][2048];  // waves 2,3 partials
  __shared__ float denbuf[2][16];

  const unsigned short* kb_ = kmat + (long)b * (NTOT * CDIM);
  const unsigned short* vb  = vT + (long)b * (CDIM * (long)NTOT);
  const unsigned short* qb  = qm + b * (16 * CDIM);

  short8 qf[4];
  #pragma unroll
  for (int kk = 0; kk < 4; ++kk)
    qf[kk] = *(const short8*)(qb + lr * CDIM + kk * 32 + lg * 8);

  f32x4 acc[8];
  #pragma unroll
  for (int i = 0; i < 8; ++i) acc[i] = (f32x4){0.f, 0.f, 0.f, 0.f};
  float den = 0.f;

  const int sl0 = lr + 16 * ((lg & 1) * 2), sl1 = sl0 + 16;
  const bool hi = (lg >= 2);

  #pragma unroll
  for (int it = 0; it < 2; ++it) {
    const int n0 = nb * 256 + (it * 4 + w) * 32;
    unsigned u[2][2];
    #pragma unroll
    for (int h = 0; h < 2; ++h) {
      f32x4 d = {0.f, 0.f, 0.f, 0.f};
      const unsigned short* krow = kb_ + (n0 + h * 16 + lr) * CDIM + lg * 8;
      #pragma unroll
      for (int kk = 0; kk < 4; ++kk) {
        short8 kf = *(const short8*)(krow + kk * 32);
        d = __builtin_amdgcn_mfma_f32_16x16x32_bf16(kf, qf[kk], d, 0, 0, 0);  // D[n][s]
      }
      float e0 = __expf(d[0]), e1 = __expf(d[1]), e2 = __expf(d[2]), e3 = __expf(d[3]);
      // softmax denominator over s (s = lr lanes), per n-register
      float c0 = e0, c1 = e1, c2 = e2, c3 = e3;
      c0 += __shfl_xor(c0, 1); c0 += __shfl_xor(c0, 2); c0 += __shfl_xor(c0, 4); c0 += __shfl_xor(c0, 8);
      c1 += __shfl_xor(c1, 1); c1 += __shfl_xor(c1, 2); c1 += __shfl_xor(c1, 4); c1 += __shfl_xor(c1, 8);
      c2 += __shfl_xor(c2, 1); c2 += __shfl_xor(c2, 2); c2 += __shfl_xor(c2, 4); c2 += __shfl_xor(c2, 8);
      c3 += __shfl_xor(c3, 1); c3 += __shfl_xor(c3, 2); c3 += __shfl_xor(c3, 4); c3 += __shfl_xor(c3, 8);
      float p0 = e0 / c0 + 1e-8f, p1 = e1 / c1 + 1e-8f,
            p2 = e2 / c2 + 1e-8f, p3 = e3 / c3 + 1e-8f;
      den += p0 + p1 + p2 + p3;   // per-s (lr) accumulation over n
      u[h][0] = pkbf(p0, p1);
      u[h][1] = pkbf(p2, p3);
    }
    // transpose p to PV B-fragment: pf word w <- (s=lr, n = lg*8 + 2w+{0,1})
    unsigned a0 = __shfl((int)u[0][0], sl0), b0 = __shfl((int)u[1][0], sl0);
    unsigned a1 = __shfl((int)u[0][1], sl0), b1 = __shfl((int)u[1][1], sl0);
    unsigned a2 = __shfl((int)u[0][0], sl1), b2 = __shfl((int)u[1][0], sl1);
    unsigned a3 = __shfl((int)u[0][1], sl1), b3 = __shfl((int)u[1][1], sl1);
    union { unsigned uw[4]; short8 s8; } pfu;
    pfu.uw[0] = hi ? b0 : a0; pfu.uw[1] = hi ? b1 : a1;
    pfu.uw[2] = hi ? b2 : a2; pfu.uw[3] = hi ? b3 : a3;
    short8 pf = pfu.s8;
    #pragma unroll
    for (int ct = 0; ct < 8; ++ct) {
      const unsigned short* vrow = vb + (ct * 16 + lr) * NTOT + n0 + lg * 8;
      short8 vf = *(const short8*)vrow;
      acc[ct] = __builtin_amdgcn_mfma_f32_16x16x32_bf16(vf, pf, acc[ct], 0, 0, 0);
    }
  }

  // den: fold lg copies (xor 16, 32) -> den[s=lr] per wave
  den += __shfl_xor(den, 16);
  den += __shfl_xor(den, 32);

  if (w >= 2) {
    float* rw_ = &redbuf[w - 2][0];
    #pragma unroll
    for (int ct = 0; ct < 8; ++ct)
      *(f32x4*)(rw_ + lr * 128 + ct * 16 + lg * 4) = acc[ct];
    if (l < 16) denbuf[w - 2][l] = den;
  }
  __syncthreads();
  if (w < 2) {
    const float* rw_ = &redbuf[w][0];
    float* outp = nump + (((long)b * 64 + nb) * 2 + w) * 2048;
    #pragma unroll
    for (int ct = 0; ct < 8; ++ct) {
      f32x4 other = *(const f32x4*)(rw_ + lr * 128 + ct * 16 + lg * 4);
      *(f32x4*)(outp + lr * 128 + ct * 16 + lg * 4) = acc[ct] + other;
    }
    if (l < 16)
      denp[(((long)b * 64 + nb) * 2 + w) * 16 + l] = den + denbuf[w][l];
  }
}

// ---- K3: reduce partials+den -> updates -> GRU -> MLP -> slots (+ q next) ----
__global__ __launch_bounds__(128) void k3_update(
    const float* __restrict__ sprev, const float* __restrict__ nump,
    const float* __restrict__ denp,
    const float* __restrict__ wih, const float* __restrict__ whh,
    const float* __restrict__ bih, const float* __restrict__ bhh,
    const float* __restrict__ w1, const float* __restrict__ b1,
    const float* __restrict__ w2, const float* __restrict__ b2,
    const float* __restrict__ lnfg, const float* __restrict__ lnfb,
    const float* __restrict__ lnsg, const float* __restrict__ lnsb,
    const float* __restrict__ Wq,
    float* __restrict__ sout, unsigned short* __restrict__ qout, const int doq) {
  const int g = blockIdx.x, b = blockIdx.y, t = threadIdx.x;
  const int sl = t >> 5, jq = (t & 31) * 4;
  const int s = g * 4 + sl;
  const long base = (long)b * 2048 + g * 512;
  __shared__ __align__(16) float sp[512];
  __shared__ __align__(16) float upd[512];
  __shared__ __align__(16) float lnb[512];
  __shared__ __align__(16) float denred[2][4];

  // den reduction: thread t = partial p, 4 s-values for this block
  f32x4 dv = *(const f32x4*)(denp + ((long)b * 128 + t) * 16 + g * 4);
  #pragma unroll
  for (int m = 1; m <= 32; m <<= 1) {
    dv[0] += __shfl_xor(dv[0], m); dv[1] += __shfl_xor(dv[1], m);
    dv[2] += __shfl_xor(dv[2], m); dv[3] += __shfl_xor(dv[3], m);
  }
  if ((t & 63) == 0) *(f32x4*)denred[t >> 6] = dv;

  f32x4 hp4 = *(const f32x4*)(sprev + base + t * 4);
  *(f32x4*)(sp + t * 4) = hp4;

  // numerator reduction over 128 partials
  f32x4 ns = {0.f, 0.f, 0.f, 0.f};
  const float* np = nump + (long)b * 262144 + s * 128 + jq;
  #pragma unroll 4
  for (int p = 0; p < 128; ++p) ns += *(const f32x4*)(np + (long)p * 2048);
  __syncthreads();
  float den_s = denred[0][sl] + denred[1][sl];
  f32x4 u4 = ns * (1.f / den_s);
  *(f32x4*)(upd + t * 4) = u4;
  __syncthreads();

  // GRU: gi = upd@wih + bih ; gh = sp@whh + bhh ; gates r,z,n
  f32x4 ir = {0,0,0,0}, iz = {0,0,0,0}, inn = {0,0,0,0};
  f32x4 hr = {0,0,0,0}, hz = {0,0,0,0}, hn = {0,0,0,0};
  const float* wih_p = wih + jq;
  const float* whh_p = whh + jq;
  const float* ur  = upd + sl * 128;
  const float* hrw = sp + sl * 128;
  for (int c = 0; c < 128; ++c) {
    float u = ur[c], h = hrw[c];
    ir  += *(const f32x4*)(wih_p + c * 384)       * u;
    iz  += *(const f32x4*)(wih_p + c * 384 + 128) * u;
    inn += *(const f32x4*)(wih_p + c * 384 + 256) * u;
    hr  += *(const f32x4*)(whh_p + c * 384)       * h;
    hz  += *(const f32x4*)(whh_p + c * 384 + 128) * h;
    hn  += *(const f32x4*)(whh_p + c * 384 + 256) * h;
  }
  ir  += *(const f32x4*)(bih + jq);
  iz  += *(const f32x4*)(bih + 128 + jq);
  inn += *(const f32x4*)(bih + 256 + jq);
  hr  += *(const f32x4*)(bhh + jq);
  hz  += *(const f32x4*)(bhh + 128 + jq);
  hn  += *(const f32x4*)(bhh + 256 + jq);
  f32x4 snew;
  #pragma unroll
  for (int i = 0; i < 4; ++i) {
    float r = sigf(ir[i] + hr[i]);
    float z = sigf(iz[i] + hz[i]);
    float n = tanhfast(inn[i] + r * hn[i]);
    snew[i] = (1.f - z) * n + z * hp4[i];
  }

  // ln_ff stats via shfl over the 32 threads of this row
  float ps = snew[0] + snew[1] + snew[2] + snew[3];
  float pq = snew[0]*snew[0] + snew[1]*snew[1] + snew[2]*snew[2] + snew[3]*snew[3];
  ps += __shfl_xor(ps, 1); ps += __shfl_xor(ps, 2); ps += __shfl_xor(ps, 4); ps += __shfl_xor(ps, 8); ps += __shfl_xor(ps, 16);
  pq += __shfl_xor(pq, 1); pq += __shfl_xor(pq, 2); pq += __shfl_xor(pq, 4); pq += __shfl_xor(pq, 8); pq += __shfl_xor(pq, 16);
  float mean = ps * (1.f / 128.f);
  float var  = pq * (1.f / 128.f) - mean * mean;
  float rstd = rsqrtf(var + 1e-5f);
  f32x4 lf = (snew - mean) * rstd * (*(const f32x4*)(lnfg + jq)) + (*(const f32x4*)(lnfb + jq));
  *(f32x4*)(lnb + t * 4) = lf;
  __syncthreads();

  // MLP layer 1 + ReLU
  f32x4 ha = {0,0,0,0};
  const float* w1p = w1 + jq;
  const float* lrow = lnb + sl * 128;
  for (int c = 0; c < 128; ++c)
    ha += *(const f32x4*)(w1p + c * 128) * lrow[c];
  ha += *(const f32x4*)(b1 + jq);
  #pragma unroll
  for (int i = 0; i < 4; ++i) ha[i] = fmaxf(ha[i], 0.f);
  *(f32x4*)(upd + t * 4) = ha;
  __syncthreads();

  // MLP layer 2 + residual
  f32x4 oa = {0,0,0,0};
  const float* w2p = w2 + jq;
  const float* hrow = upd + sl * 128;
  for (int c = 0; c < 128; ++c)
    oa += *(const f32x4*)(w2p + c * 128) * hrow[c];
  oa += *(const f32x4*)(b2 + jq);
  f32x4 sf = snew + oa;
  *(f32x4*)(sout + base + t * 4) = sf;

  if (doq) {
    float qs = sf[0] + sf[1] + sf[2] + sf[3];
    float qz = sf[0]*sf[0] + sf[1]*sf[1] + sf[2]*sf[2] + sf[3]*sf[3];
    qs += __shfl_xor(qs, 1); qs += __shfl_xor(qs, 2); qs += __shfl_xor(qs, 4); qs += __shfl_xor(qs, 8); qs += __shfl_xor(qs, 16);
    qz += __shfl_xor(qz, 1); qz += __shfl_xor(qz, 2); qz += __shfl_xor(qz, 4); qz += __shfl_xor(qz, 8); qz += __shfl_xor(qz, 16);
    float m2 = qs * (1.f / 128.f);
    float v2 = qz * (1.f / 128.f) - m2 * m2;
    float rs2 = rsqrtf(v2 + 1e-5f);
    f32x4 lq = (sf - m2) * rs2 * (*(const f32x4*)(lnsg + jq)) + (*(const f32x4*)(lnsb + jq));
    *(f32x4*)(sp + t * 4) = lq;   // reuse sp
    __syncthreads();
    f32x4 qa = {0,0,0,0};
    const float* wqp = Wq + jq;
    const float* qrow = sp + sl * 128;
    for (int c = 0; c < 128; ++c)
      qa += *(const f32x4*)(wqp + c * 128) * qrow[c];
    qa *= 0.08838834764831845f;
    u32x2 pk = { pkbf(qa[0], qa[1]), pkbf(qa[2], qa[3]) };
    *(u32x2*)(qout + base + t * 4) = pk;
  }
}

extern "C" void kernel_launch(void* const* d_in, const int* in_sizes, int n_in,
                              void* d_out, int out_size, void* d_ws, size_t ws_size,
                              hipStream_t stream) {
  (void)in_sizes; (void)n_in; (void)out_size; (void)ws_size;
  const float* slots = (const float*)d_in[0];
  const float* inputs = (const float*)d_in[1];
  const float* Wq  = (const float*)d_in[2];
  const float* Wk  = (const float*)d_in[3];
  const float* Wv  = (const float*)d_in[4];
  const float* wih = (const float*)d_in[5];
  const float* whh = (const float*)d_in[6];
  const float* bih = (const float*)d_in[7];
  const float* bhh = (const float*)d_in[8];
  const float* w1  = (const float*)d_in[9];
  const float* b1  = (const float*)d_in[10];
  const float* w2  = (const float*)d_in[11];
  const float* b2  = (const float*)d_in[12];
  const float* lnig = (const float*)d_in[13];
  const float* lnib = (const float*)d_in[14];
  const float* lnsg = (const float*)d_in[15];
  const float* lnsb = (const float*)d_in[16];
  const float* lnfg = (const float*)d_in[17];
  const float* lnfb = (const float*)d_in[18];

  char* ws = (char*)d_ws;
  unsigned short* kmat = (unsigned short*)(ws);
  unsigned short* vT   = (unsigned short*)(ws + 134217728L);
  unsigned short* qbuf = (unsigned short*)(ws + 268435456L);
  unsigned short* wpk  = (unsigned short*)(ws + 268566528L);
  float* nump = (float*)(ws + 268632064L);
  float* denp = (float*)(ws + 302186496L);
  float* sbuf = (float*)(ws + 302710784L);

  k0_prep<<<128, 256, 0, stream>>>(Wk, Wv, wpk);
  k1_lnkv<<<8192, 256, 0, stream>>>(inputs, lnig, lnib, wpk, kmat, vT);
  kq_init<<<32, 512, 0, stream>>>(slots, lnsg, lnsb, Wq, qbuf);
  for (int it = 0; it < 3; ++it) {
    k2_attn<<<dim3(64, 32), 256, 0, stream>>>(kmat, vT, qbuf, nump, denp);
    const float* sprev = (it == 0) ? slots : sbuf;
    float* sdst = (it == 2) ? (float*)d_out : sbuf;
    k3_update<<<dim3(4, 32), 128, 0, stream>>>(sprev, nump, denp, wih, whh, bih, bhh,
                                      w1, b1, w2, b2, lnfg, lnfb, lnsg, lnsb, Wq,
                                      sdst, qbuf, (it < 2) ? 1 : 0);
  }
}

// Round 5
// 580.140 us; speedup vs baseline: 1.1616x; 1.0171x over previous
//
#include <hip/hip_runtime.h>

// SlotAttention MI355X implementation, v5.
// k0: fold ln_in into weights: W' = diag(g)W (MFMA-fragment-packed bf16),
//     u = colsum(g*W), v = b@W  (f32).  LN(x)@W = r*(x@W') - r*m*u + v.
// k1: raw-x fragment loads -> stats (4 shfl) -> MFMA -> affine epilogue ->
//     LDS-bounce -> fully-coalesced stores of kmat [b][n][c] and vT [b][c][n].
// kq: q from initial slots. 3x { k2: dots D[s][n] -> in-register softmax
// (2 shfl) -> LDS p-transpose -> PV MFMA -> partials; k3: reduce -> GRU ->
// MLP -> slots (+ q next) }.
// Workspace (~288.7 MiB): see kernel_launch.

#define NTOT 16384
#define CDIM 128

using short8 = __attribute__((ext_vector_type(8))) short;
using f32x4  = __attribute__((ext_vector_type(4))) float;
using u32x2  = __attribute__((ext_vector_type(2))) unsigned;

__device__ __forceinline__ unsigned pkbf(float lo, float hi) {
  unsigned r;
  asm("v_cvt_pk_bf16_f32 %0, %1, %2" : "=v"(r) : "v"(lo), "v"(hi));
  return r;
}
__device__ __forceinline__ unsigned short f2bf(float x) {
  union { float f; unsigned u; } v; v.f = x;
  unsigned r = v.u + 0x7FFFu + ((v.u >> 16) & 1u);
  return (unsigned short)(r >> 16);
}
__device__ __forceinline__ float sigf(float x) { return 1.f / (1.f + __expf(-x)); }
__device__ __forceinline__ float tanhfast(float x) {
  x = fminf(fmaxf(x, -15.f), 15.f);
  float e = __expf(2.f * x);
  return (e - 1.f) / (e + 1.f);
}

// ---- K0: W' = diag(g)W packed to fragment order; u = colsum(W'); v = b@W ----
// wpk[which][ct][kb][lane][j] = g[cin]*W[cin][cout], cin=kb*32+(lane>>4)*8+j, cout=ct*16+(lane&15)
__global__ void k0_prep(const float* __restrict__ Wk, const float* __restrict__ Wv,
                        const float* __restrict__ g, const float* __restrict__ bb,
                        unsigned short* __restrict__ wpk,
                        float* __restrict__ uvec, float* __restrict__ vvec) {
  const int t = threadIdx.x;              // 256 threads, 1 block
  const int which = t >> 7, cout = t & 127;
  const int ct = cout >> 4, lr = cout & 15;
  const float* W = which ? Wv : Wk;
  float u = 0.f, v = 0.f;
  for (int cin = 0; cin < 128; ++cin) {
    float wv = W[cin * 128 + cout];
    float gw = g[cin] * wv;
    u += gw;
    v += bb[cin] * wv;
    int kb = cin >> 5, lg = (cin >> 3) & 3, j = cin & 7;
    wpk[(((which * 8 + ct) * 4 + kb) * 64 + lg * 16 + lr) * 8 + j] = f2bf(gw);
  }
  uvec[t] = u;
  vvec[t] = v;
}

// ---- K1: x -> stats -> MFMA vs W' -> affine -> LDS bounce -> coalesced stores ----
__global__ __launch_bounds__(256) void k1_lnkv(
    const float* __restrict__ in, const unsigned short* __restrict__ wpk,
    const float* __restrict__ uvec, const float* __restrict__ vvec,
    unsigned short* __restrict__ kmat, unsigned short* __restrict__ vT) {
  __shared__ unsigned short klds[4][16][132];  // per-wave [n][c], pad 4
  __shared__ unsigned short vlds[128][68];     // block [c][n], pad 4
  const int t = threadIdx.x, w = t >> 6, l = t & 63, lr = l & 15, lg = l >> 4;
  const long rowbase = (long)blockIdx.x * 64;
  const long b = rowbase >> 14;

  // fragment-order loads: lane holds row (w*16+lr), cols kb*32+lg*8..+7
  const float* src = in + (rowbase + w * 16 + lr) * CDIM;
  f32x4 x[4][2];
  #pragma unroll
  for (int kb = 0; kb < 4; ++kb) {
    x[kb][0] = *(const f32x4*)(src + kb * 32 + lg * 8);
    x[kb][1] = *(const f32x4*)(src + kb * 32 + lg * 8 + 4);
  }
  float s1 = 0.f, s2 = 0.f;
  #pragma unroll
  for (int kb = 0; kb < 4; ++kb)
    #pragma unroll
    for (int h = 0; h < 2; ++h)
      #pragma unroll
      for (int i = 0; i < 4; ++i) { float xx = x[kb][h][i]; s1 += xx; s2 += xx * xx; }
  s1 += __shfl_xor(s1, 16); s1 += __shfl_xor(s1, 32);
  s2 += __shfl_xor(s2, 16); s2 += __shfl_xor(s2, 32);
  const float mean = s1 * (1.f / 128.f);
  const float rstd = rsqrtf(s2 * (1.f / 128.f) - mean * mean + 1e-5f);

  short8 af[4];
  #pragma unroll
  for (int kb = 0; kb < 4; ++kb) {
    union { unsigned uw[4]; short8 s8; } c;
    c.uw[0] = pkbf(x[kb][0][0], x[kb][0][1]);
    c.uw[1] = pkbf(x[kb][0][2], x[kb][0][3]);
    c.uw[2] = pkbf(x[kb][1][0], x[kb][1][1]);
    c.uw[3] = pkbf(x[kb][1][2], x[kb][1][3]);
    af[kb] = c.s8;
  }
  // stats broadcast to D rows n = lg*4+r
  float mr[4], rr[4];
  #pragma unroll
  for (int r = 0; r < 4; ++r) {
    mr[r] = __shfl(mean, lg * 4 + r);
    rr[r] = __shfl(rstd, lg * 4 + r);
  }

  // k pass: D[n][cout], n=lg*4+r, cout=ct*16+lr
  #pragma unroll
  for (int ct = 0; ct < 8; ++ct) {
    f32x4 a = {0.f, 0.f, 0.f, 0.f};
    #pragma unroll
    for (int kb = 0; kb < 4; ++kb) {
      short8 wf = *(const short8*)(wpk + ((ct * 4 + kb) * 64 + l) * 8);
      a = __builtin_amdgcn_mfma_f32_16x16x32_bf16(af[kb], wf, a, 0, 0, 0);
    }
    float uk = uvec[ct * 16 + lr], vk = vvec[ct * 16 + lr];
    unsigned w01 = pkbf(rr[0] * (a[0] - mr[0] * uk) + vk,
                        rr[1] * (a[1] - mr[1] * uk) + vk);
    unsigned w23 = pkbf(rr[2] * (a[2] - mr[2] * uk) + vk,
                        rr[3] * (a[3] - mr[3] * uk) + vk);
    klds[w][lg * 4 + 0][ct * 16 + lr] = (unsigned short)w01;
    klds[w][lg * 4 + 1][ct * 16 + lr] = (unsigned short)(w01 >> 16);
    klds[w][lg * 4 + 2][ct * 16 + lr] = (unsigned short)w23;
    klds[w][lg * 4 + 3][ct * 16 + lr] = (unsigned short)(w23 >> 16);
  }
  asm volatile("" ::: "memory");  // same-wave LDS RAW; DS in-order
  // coalesced kmat store: wave writes its 16 contiguous rows (4x 1KB insts)
  unsigned short* kdst = kmat + (rowbase + w * 16) * CDIM;
  #pragma unroll
  for (int i = 0; i < 4; ++i) {
    int row = i * 4 + (l >> 4), ch = (l & 15) * 8;
    short8 vv = *(const short8*)&klds[w][row][ch];
    *(short8*)(kdst + row * CDIM + ch) = vv;
  }

  // v pass (swapped): D[cout][n], cout=ct*16+lg*4+r, n=lr (lane's own row stats)
  #pragma unroll
  for (int ct = 0; ct < 8; ++ct) {
    f32x4 a = {0.f, 0.f, 0.f, 0.f};
    #pragma unroll
    for (int kb = 0; kb < 4; ++kb) {
      short8 wf = *(const short8*)(wpk + (((8 + ct) * 4 + kb) * 64 + l) * 8);
      a = __builtin_amdgcn_mfma_f32_16x16x32_bf16(wf, af[kb], a, 0, 0, 0);
    }
    f32x4 u4 = *(const f32x4*)(uvec + 128 + ct * 16 + lg * 4);
    f32x4 v4 = *(const f32x4*)(vvec + 128 + ct * 16 + lg * 4);
    unsigned w01 = pkbf(rstd * (a[0] - mean * u4[0]) + v4[0],
                        rstd * (a[1] - mean * u4[1]) + v4[1]);
    unsigned w23 = pkbf(rstd * (a[2] - mean * u4[2]) + v4[2],
                        rstd * (a[3] - mean * u4[3]) + v4[3]);
    vlds[ct * 16 + lg * 4 + 0][w * 16 + lr] = (unsigned short)w01;
    vlds[ct * 16 + lg * 4 + 1][w * 16 + lr] = (unsigned short)(w01 >> 16);
    vlds[ct * 16 + lg * 4 + 2][w * 16 + lr] = (unsigned short)w23;
    vlds[ct * 16 + lg * 4 + 3][w * 16 + lr] = (unsigned short)(w23 >> 16);
  }
  __syncthreads();
  // coalesced vT store: 128B-contiguous per c-row, 8 c-rows per inst
  unsigned short* vTb = vT + b * (CDIM * (long)NTOT) + (rowbase & 16383);
  #pragma unroll
  for (int i = 0; i < 4; ++i) {
    int c = i * 32 + (t >> 3), n8 = (t & 7) * 8;
    short8 vv = *(const short8*)&vlds[c][n8];
    *(short8*)(vTb + (long)c * NTOT + n8) = vv;
  }
}

// ---- Kq: q = (LN_s(slots) @ Wq) / sqrt(C) -> bf16 (initial iteration) ----
__global__ __launch_bounds__(512) void kq_init(
    const float* __restrict__ slots, const float* __restrict__ lnsg,
    const float* __restrict__ lnsb, const float* __restrict__ Wq,
    unsigned short* __restrict__ qout) {
  const int b = blockIdx.x, t = threadIdx.x;
  const int s = t >> 5, jq = (t & 31) * 4;
  __shared__ __align__(16) float lnq[2048];
  f32x4 x4 = *(const f32x4*)(slots + b * 2048 + t * 4);
  float ps = x4[0] + x4[1] + x4[2] + x4[3];
  float pq = x4[0]*x4[0] + x4[1]*x4[1] + x4[2]*x4[2] + x4[3]*x4[3];
  ps += __shfl_xor(ps, 1); ps += __shfl_xor(ps, 2); ps += __shfl_xor(ps, 4); ps += __shfl_xor(ps, 8); ps += __shfl_xor(ps, 16);
  pq += __shfl_xor(pq, 1); pq += __shfl_xor(pq, 2); pq += __shfl_xor(pq, 4); pq += __shfl_xor(pq, 8); pq += __shfl_xor(pq, 16);
  float mean = ps * (1.f / 128.f);
  float var  = pq * (1.f / 128.f) - mean * mean;
  float rstd = rsqrtf(var + 1e-5f);
  f32x4 l4 = (x4 - mean) * rstd * (*(const f32x4*)(lnsg + jq)) + (*(const f32x4*)(lnsb + jq));
  *(f32x4*)(lnq + t * 4) = l4;
  __syncthreads();
  f32x4 qa = {0.f, 0.f, 0.f, 0.f};
  const float* wqp = Wq + jq;
  const float* qrow = lnq + s * 128;
  for (int c = 0; c < 128; ++c)
    qa += *(const f32x4*)(wqp + c * 128) * qrow[c];
  qa *= 0.08838834764831845f;  // 1/sqrt(128)
  u32x2 pk = { pkbf(qa[0], qa[1]), pkbf(qa[2], qa[3]) };
  *(u32x2*)(qout + b * 2048 + t * 4) = pk;
}

// ---- K2: dots D[s][n] -> in-reg softmax -> LDS p-transpose -> PV ----
__global__ __launch_bounds__(256) void k2_attn(
    const unsigned short* __restrict__ kmat, const unsigned short* __restrict__ vT,
    const unsigned short* __restrict__ qm,
    float* __restrict__ nump, float* __restrict__ denp) {
  const int nb = blockIdx.x, b = blockIdx.y;
  const int t = threadIdx.x, w = t >> 6, l = t & 63, lr = l & 15, lg = l >> 4;
  __shared__ unsigned short pbuf[4][16][40];   // per-wave [s][n 0..31], pad 8
  __shared__ __align__(16) float redbuf[2][2048];
  __shared__ float denbuf[2][16];

  const unsigned short* kb_ = kmat + (long)b * (NTOT * CDIM);
  const unsigned short* vb  = vT + (long)b * (CDIM * (long)NTOT);
  const unsigned short* qb  = qm + b * (16 * CDIM);

  short8 qf[4];
  #pragma unroll
  for (int kk = 0; kk < 4; ++kk)
    qf[kk] = *(const short8*)(qb + lr * CDIM + kk * 32 + lg * 8);

  f32x4 acc[8];
  #pragma unroll
  for (int i = 0; i < 8; ++i) acc[i] = (f32x4){0.f, 0.f, 0.f, 0.f};
  f32x4 dacc = {0.f, 0.f, 0.f, 0.f};  // den per s=lg*4+r, own n=lr

  #pragma unroll
  for (int it = 0; it < 2; ++it) {
    const int n0 = nb * 256 + (it * 4 + w) * 32;
    #pragma unroll
    for (int h = 0; h < 2; ++h) {
      f32x4 d = {0.f, 0.f, 0.f, 0.f};
      const unsigned short* krow = kb_ + (n0 + h * 16 + lr) * CDIM + lg * 8;
      #pragma unroll
      for (int kk = 0; kk < 4; ++kk) {
        short8 kf = *(const short8*)(krow + kk * 32);
        d = __builtin_amdgcn_mfma_f32_16x16x32_bf16(qf[kk], kf, d, 0, 0, 0);  // D[s][n]
      }
      float e0 = __expf(d[0]), e1 = __expf(d[1]), e2 = __expf(d[2]), e3 = __expf(d[3]);
      float cs = e0 + e1 + e2 + e3;            // sum over s: 4 regs in-lane...
      cs += __shfl_xor(cs, 16);                // ...then over lg groups
      cs += __shfl_xor(cs, 32);
      float inv = 1.f / cs;
      float p0 = e0 * inv + 1e-8f, p1 = e1 * inv + 1e-8f,
            p2 = e2 * inv + 1e-8f, p3 = e3 * inv + 1e-8f;
      dacc[0] += p0; dacc[1] += p1; dacc[2] += p2; dacc[3] += p3;
      unsigned w01 = pkbf(p0, p1), w23 = pkbf(p2, p3);
      pbuf[w][lg * 4 + 0][h * 16 + lr] = (unsigned short)w01;
      pbuf[w][lg * 4 + 1][h * 16 + lr] = (unsigned short)(w01 >> 16);
      pbuf[w][lg * 4 + 2][h * 16 + lr] = (unsigned short)w23;
      pbuf[w][lg * 4 + 3][h * 16 + lr] = (unsigned short)(w23 >> 16);
    }
    asm volatile("" ::: "memory");  // same-wave LDS RAW
    short8 pf = *(const short8*)&pbuf[w][lr][lg * 8];  // B-frag: col=s=lr, k=n
    #pragma unroll
    for (int ct = 0; ct < 8; ++ct) {
      const unsigned short* vrow = vb + (ct * 16 + lr) * NTOT + n0 + lg * 8;
      short8 vf = *(const short8*)vrow;
      acc[ct] = __builtin_amdgcn_mfma_f32_16x16x32_bf16(vf, pf, acc[ct], 0, 0, 0);
    }
    asm volatile("" ::: "memory");  // keep next it's writes after this read
  }

  // den: reduce over n (lr lanes); all lanes end with den for s=lg*4+r
  #pragma unroll
  for (int m = 1; m <= 8; m <<= 1) {
    dacc[0] += __shfl_xor(dacc[0], m); dacc[1] += __shfl_xor(dacc[1], m);
    dacc[2] += __shfl_xor(dacc[2], m); dacc[3] += __shfl_xor(dacc[3], m);
  }

  if (w >= 2) {
    float* rw_ = &redbuf[w - 2][0];
    #pragma unroll
    for (int ct = 0; ct < 8; ++ct)
      *(f32x4*)(rw_ + lr * 128 + ct * 16 + lg * 4) = acc[ct];
    if (lr == 0) {
      #pragma unroll
      for (int r = 0; r < 4; ++r) denbuf[w - 2][lg * 4 + r] = dacc[r];
    }
  }
  __syncthreads();
  if (w < 2) {
    const float* rw_ = &redbuf[w][0];
    float* outp = nump + (((long)b * 64 + nb) * 2 + w) * 2048;
    #pragma unroll
    for (int ct = 0; ct < 8; ++ct) {
      f32x4 other = *(const f32x4*)(rw_ + lr * 128 + ct * 16 + lg * 4);
      *(f32x4*)(outp + lr * 128 + ct * 16 + lg * 4) = acc[ct] + other;
    }
    if (lr == 0) {
      #pragma unroll
      for (int r = 0; r < 4; ++r)
        denp[(((long)b * 64 + nb) * 2 + w) * 16 + lg * 4 + r] =
            dacc[r] + denbuf[w][lg * 4 + r];
    }
  }
}

// ---- K3: reduce partials+den -> updates -> GRU -> MLP -> slots (+ q next) ----
__global__ __launch_bounds__(128) void k3_update(
    const float* __restrict__ sprev, const float* __restrict__ nump,
    const float* __restrict__ denp,
    const float* __restrict__ wih, const float* __restrict__ whh,
    const float* __restrict__ bih, const float* __restrict__ bhh,
    const float* __restrict__ w1, const float* __restrict__ b1,
    const float* __restrict__ w2, const float* __restrict__ b2,
    const float* __restrict__ lnfg, const float* __restrict__ lnfb,
    const float* __restrict__ lnsg, const float* __restrict__ lnsb,
    const float* __restrict__ Wq,
    float* __restrict__ sout, unsigned short* __restrict__ qout, const int doq) {
  const int g = blockIdx.x, b = blockIdx.y, t = threadIdx.x;
  const int sl = t >> 5, jq = (t & 31) * 4;
  const int s = g * 4 + sl;
  const long base = (long)b * 2048 + g * 512;
  __shared__ __align__(16) float sp[512];
  __shared__ __align__(16) float upd[512];
  __shared__ __align__(16) float lnb[512];
  __shared__ __align__(16) float denred[2][4];

  f32x4 dv = *(const f32x4*)(denp + ((long)b * 128 + t) * 16 + g * 4);
  #pragma unroll
  for (int m = 1; m <= 32; m <<= 1) {
    dv[0] += __shfl_xor(dv[0], m); dv[1] += __shfl_xor(dv[1], m);
    dv[2] += __shfl_xor(dv[2], m); dv[3] += __shfl_xor(dv[3], m);
  }
  if ((t & 63) == 0) *(f32x4*)denred[t >> 6] = dv;

  f32x4 hp4 = *(const f32x4*)(sprev + base + t * 4);
  *(f32x4*)(sp + t * 4) = hp4;

  f32x4 ns = {0.f, 0.f, 0.f, 0.f};
  const float* np = nump + (long)b * 262144 + s * 128 + jq;
  #pragma unroll 4
  for (int p = 0; p < 128; ++p) ns += *(const f32x4*)(np + (long)p * 2048);
  __syncthreads();
  float den_s = denred[0][sl] + denred[1][sl];
  f32x4 u4 = ns * (1.f / den_s);
  *(f32x4*)(upd + t * 4) = u4;
  __syncthreads();

  f32x4 ir = {0,0,0,0}, iz = {0,0,0,0}, inn = {0,0,0,0};
  f32x4 hr = {0,0,0,0}, hz = {0,0,0,0}, hn = {0,0,0,0};
  const float* wih_p = wih + jq;
  const float* whh_p = whh + jq;
  const float* ur  = upd + sl * 128;
  const float* hrw = sp + sl * 128;
  for (int c = 0; c < 128; ++c) {
    float u = ur[c], h = hrw[c];
    ir  += *(const f32x4*)(wih_p + c * 384)       * u;
    iz  += *(const f32x4*)(wih_p + c * 384 + 128) * u;
    inn += *(const f32x4*)(wih_p + c * 384 + 256) * u;
    hr  += *(const f32x4*)(whh_p + c * 384)       * h;
    hz  += *(const f32x4*)(whh_p + c * 384 + 128) * h;
    hn  += *(const f32x4*)(whh_p + c * 384 + 256) * h;
  }
  ir  += *(const f32x4*)(bih + jq);
  iz  += *(const f32x4*)(bih + 128 + jq);
  inn += *(const f32x4*)(bih + 256 + jq);
  hr  += *(const f32x4*)(bhh + jq);
  hz  += *(const f32x4*)(bhh + 128 + jq);
  hn  += *(const f32x4*)(bhh + 256 + jq);
  f32x4 snew;
  #pragma unroll
  for (int i = 0; i < 4; ++i) {
    float r = sigf(ir[i] + hr[i]);
    float z = sigf(iz[i] + hz[i]);
    float n = tanhfast(inn[i] + r * hn[i]);
    snew[i] = (1.f - z) * n + z * hp4[i];
  }

  float ps = snew[0] + snew[1] + snew[2] + snew[3];
  float pq = snew[0]*snew[0] + snew[1]*snew[1] + snew[2]*snew[2] + snew[3]*snew[3];
  ps += __shfl_xor(ps, 1); ps += __shfl_xor(ps, 2); ps += __shfl_xor(ps, 4); ps += __shfl_xor(ps, 8); ps += __shfl_xor(ps, 16);
  pq += __shfl_xor(pq, 1); pq += __shfl_xor(pq, 2); pq += __shfl_xor(pq, 4); pq += __shfl_xor(pq, 8); pq += __shfl_xor(pq, 16);
  float mean = ps * (1.f / 128.f);
  float var  = pq * (1.f / 128.f) - mean * mean;
  float rstd = rsqrtf(var + 1e-5f);
  f32x4 lf = (snew - mean) * rstd * (*(const f32x4*)(lnfg + jq)) + (*(const f32x4*)(lnfb + jq));
  *(f32x4*)(lnb + t * 4) = lf;
  __syncthreads();

  f32x4 ha = {0,0,0,0};
  const float* w1p = w1 + jq;
  const float* lrow = lnb + sl * 128;
  for (int c = 0; c < 128; ++c)
    ha += *(const f32x4*)(w1p + c * 128) * lrow[c];
  ha += *(const f32x4*)(b1 + jq);
  #pragma unroll
  for (int i = 0; i < 4; ++i) ha[i] = fmaxf(ha[i], 0.f);
  *(f32x4*)(upd + t * 4) = ha;
  __syncthreads();

  f32x4 oa = {0,0,0,0};
  const float* w2p = w2 + jq;
  const float* hrow = upd + sl * 128;
  for (int c = 0; c < 128; ++c)
    oa += *(const f32x4*)(w2p + c * 128) * hrow[c];
  oa += *(const f32x4*)(b2 + jq);
  f32x4 sf = snew + oa;
  *(f32x4*)(sout + base + t * 4) = sf;

  if (doq) {
    float qs = sf[0] + sf[1] + sf[2] + sf[3];
    float qz = sf[0]*sf[0] + sf[1]*sf[1] + sf[2]*sf[2] + sf[3]*sf[3];
    qs += __shfl_xor(qs, 1); qs += __shfl_xor(qs, 2); qs += __shfl_xor(qs, 4); qs += __shfl_xor(qs, 8); qs += __shfl_xor(qs, 16);
    qz += __shfl_xor(qz, 1); qz += __shfl_xor(qz, 2); qz += __shfl_xor(qz, 4); qz += __shfl_xor(qz, 8); qz += __shfl_xor(qz, 16);
    float m2 = qs * (1.f / 128.f);
    float v2 = qz * (1.f / 128.f) - m2 * m2;
    float rs2 = rsqrtf(v2 + 1e-5f);
    f32x4 lq = (sf - m2) * rs2 * (*(const f32x4*)(lnsg + jq)) + (*(const f32x4*)(lnsb + jq));
    *(f32x4*)(sp + t * 4) = lq;
    __syncthreads();
    f32x4 qa = {0,0,0,0};
    const float* wqp = Wq + jq;
    const float* qrow = sp + sl * 128;
    for (int c = 0; c < 128; ++c)
      qa += *(const f32x4*)(wqp + c * 128) * qrow[c];
    qa *= 0.08838834764831845f;
    u32x2 pk = { pkbf(qa[0], qa[1]), pkbf(qa[2], qa[3]) };
    *(u32x2*)(qout + base + t * 4) = pk;
  }
}

extern "C" void kernel_launch(void* const* d_in, const int* in_sizes, int n_in,
                              void* d_out, int out_size, void* d_ws, size_t ws_size,
                              hipStream_t stream) {
  (void)in_sizes; (void)n_in; (void)out_size; (void)ws_size;
  const float* slots = (const float*)d_in[0];
  const float* inputs = (const float*)d_in[1];
  const float* Wq  = (const float*)d_in[2];
  const float* Wk  = (const float*)d_in[3];
  const float* Wv  = (const float*)d_in[4];
  const float* wih = (const float*)d_in[5];
  const float* whh = (const float*)d_in[6];
  const float* bih = (const float*)d_in[7];
  const float* bhh = (const float*)d_in[8];
  const float* w1  = (const float*)d_in[9];
  const float* b1  = (const float*)d_in[10];
  const float* w2  = (const float*)d_in[11];
  const float* b2  = (const float*)d_in[12];
  const float* lnig = (const float*)d_in[13];
  const float* lnib = (const float*)d_in[14];
  const float* lnsg = (const float*)d_in[15];
  const float* lnsb = (const float*)d_in[16];
  const float* lnfg = (const float*)d_in[17];
  const float* lnfb = (const float*)d_in[18];

  char* ws = (char*)d_ws;
  unsigned short* kmat = (unsigned short*)(ws);
  unsigned short* vT   = (unsigned short*)(ws + 134217728L);
  unsigned short* qbuf = (unsigned short*)(ws + 268435456L);
  unsigned short* wpk  = (unsigned short*)(ws + 268566528L);
  float* uvec = (float*)(ws + 268632064L);
  float* vvec = (float*)(ws + 268633088L);
  float* nump = (float*)(ws + 268634112L);
  float* denp = (float*)(ws + 302188544L);
  float* sbuf = (float*)(ws + 302450688L);

  k0_prep<<<1, 256, 0, stream>>>(Wk, Wv, lnig, lnib, wpk, uvec, vvec);
  k1_lnkv<<<8192, 256, 0, stream>>>(inputs, wpk, uvec, vvec, kmat, vT);
  kq_init<<<32, 512, 0, stream>>>(slots, lnsg, lnsb, Wq, qbuf);
  for (int it = 0; it < 3; ++it) {
    k2_attn<<<dim3(64, 32), 256, 0, stream>>>(kmat, vT, qbuf, nump, denp);
    const float* sprev = (it == 0) ? slots : sbuf;
    float* sdst = (it == 2) ? (float*)d_out : sbuf;
    k3_update<<<dim3(4, 32), 128, 0, stream>>>(sprev, nump, denp, wih, whh, bih, bhh,
                                      w1, b1, w2, b2, lnfg, lnfb, lnsg, lnsb, Wq,
                                      sdst, qbuf, (it < 2) ? 1 : 0);
  }
}

// Round 6
// 563.996 us; speedup vs baseline: 1.1949x; 1.0286x over previous
//
#include <hip/hip_runtime.h>

// SlotAttention MI355X implementation, v6.
// Changes vs v5: (1) k1 LDS union (klds/vlds share one 17.4KB buffer in
// disjoint phases) -> 8 blocks/CU instead of 4 (latency-concurrency fix);
// (2) k2 pbuf double-buffered per n-tile + compiler fences removed so global
// loads pipeline across tiles.
// Workspace (~288.7 MiB): see kernel_launch.

#define NTOT 16384
#define CDIM 128

using short8 = __attribute__((ext_vector_type(8))) short;
using f32x4  = __attribute__((ext_vector_type(4))) float;
using u32x2  = __attribute__((ext_vector_type(2))) unsigned;

__device__ __forceinline__ unsigned pkbf(float lo, float hi) {
  unsigned r;
  asm("v_cvt_pk_bf16_f32 %0, %1, %2" : "=v"(r) : "v"(lo), "v"(hi));
  return r;
}
__device__ __forceinline__ unsigned short f2bf(float x) {
  union { float f; unsigned u; } v; v.f = x;
  unsigned r = v.u + 0x7FFFu + ((v.u >> 16) & 1u);
  return (unsigned short)(r >> 16);
}
__device__ __forceinline__ float sigf(float x) { return 1.f / (1.f + __expf(-x)); }
__device__ __forceinline__ float tanhfast(float x) {
  x = fminf(fmaxf(x, -15.f), 15.f);
  float e = __expf(2.f * x);
  return (e - 1.f) / (e + 1.f);
}

// ---- K0: W' = diag(g)W packed to fragment order; u = colsum(W'); v = b@W ----
__global__ void k0_prep(const float* __restrict__ Wk, const float* __restrict__ Wv,
                        const float* __restrict__ g, const float* __restrict__ bb,
                        unsigned short* __restrict__ wpk,
                        float* __restrict__ uvec, float* __restrict__ vvec) {
  const int t = threadIdx.x;              // 256 threads, 1 block
  const int which = t >> 7, cout = t & 127;
  const int ct = cout >> 4, lr = cout & 15;
  const float* W = which ? Wv : Wk;
  float u = 0.f, v = 0.f;
  for (int cin = 0; cin < 128; ++cin) {
    float wv = W[cin * 128 + cout];
    float gw = g[cin] * wv;
    u += gw;
    v += bb[cin] * wv;
    int kb = cin >> 5, lg = (cin >> 3) & 3, j = cin & 7;
    wpk[(((which * 8 + ct) * 4 + kb) * 64 + lg * 16 + lr) * 8 + j] = f2bf(gw);
  }
  uvec[t] = u;
  vvec[t] = v;
}

// ---- K1: x -> stats -> MFMA vs W' -> affine -> LDS bounce -> coalesced stores ----
__global__ __launch_bounds__(256, 6) void k1_lnkv(
    const float* __restrict__ in, const unsigned short* __restrict__ wpk,
    const float* __restrict__ uvec, const float* __restrict__ vvec,
    unsigned short* __restrict__ kmat, unsigned short* __restrict__ vT) {
  // union: phase A = klds (per-wave [16][132] ushort, 4224B x 4 = 16.9KB)
  //        phase B = vlds (block [128][68] ushort, 17.4KB)
  __shared__ __align__(16) char smem[17408];
  const int t = threadIdx.x, w = t >> 6, l = t & 63, lr = l & 15, lg = l >> 4;
  unsigned short (*klds)[132] = (unsigned short(*)[132])(smem + w * 4224);
  unsigned short (*vlds)[68]  = (unsigned short(*)[68])smem;
  const long rowbase = (long)blockIdx.x * 64;
  const long b = rowbase >> 14;

  // fragment-order loads: lane holds row (w*16+lr), cols kb*32+lg*8..+7
  const float* src = in + (rowbase + w * 16 + lr) * CDIM;
  f32x4 x[4][2];
  #pragma unroll
  for (int kb = 0; kb < 4; ++kb) {
    x[kb][0] = *(const f32x4*)(src + kb * 32 + lg * 8);
    x[kb][1] = *(const f32x4*)(src + kb * 32 + lg * 8 + 4);
  }
  float s1 = 0.f, s2 = 0.f;
  #pragma unroll
  for (int kb = 0; kb < 4; ++kb)
    #pragma unroll
    for (int h = 0; h < 2; ++h)
      #pragma unroll
      for (int i = 0; i < 4; ++i) { float xx = x[kb][h][i]; s1 += xx; s2 += xx * xx; }
  s1 += __shfl_xor(s1, 16); s1 += __shfl_xor(s1, 32);
  s2 += __shfl_xor(s2, 16); s2 += __shfl_xor(s2, 32);
  const float mean = s1 * (1.f / 128.f);
  const float rstd = rsqrtf(s2 * (1.f / 128.f) - mean * mean + 1e-5f);

  short8 af[4];
  #pragma unroll
  for (int kb = 0; kb < 4; ++kb) {
    union { unsigned uw[4]; short8 s8; } c;
    c.uw[0] = pkbf(x[kb][0][0], x[kb][0][1]);
    c.uw[1] = pkbf(x[kb][0][2], x[kb][0][3]);
    c.uw[2] = pkbf(x[kb][1][0], x[kb][1][1]);
    c.uw[3] = pkbf(x[kb][1][2], x[kb][1][3]);
    af[kb] = c.s8;
  }
  // stats broadcast to D rows n = lg*4+r
  float mr[4], rr[4];
  #pragma unroll
  for (int r = 0; r < 4; ++r) {
    mr[r] = __shfl(mean, lg * 4 + r);
    rr[r] = __shfl(rstd, lg * 4 + r);
  }

  // k pass: D[n][cout], n=lg*4+r, cout=ct*16+lr
  #pragma unroll
  for (int ct = 0; ct < 8; ++ct) {
    f32x4 a = {0.f, 0.f, 0.f, 0.f};
    #pragma unroll
    for (int kb = 0; kb < 4; ++kb) {
      short8 wf = *(const short8*)(wpk + ((ct * 4 + kb) * 64 + l) * 8);
      a = __builtin_amdgcn_mfma_f32_16x16x32_bf16(af[kb], wf, a, 0, 0, 0);
    }
    float uk = uvec[ct * 16 + lr], vk = vvec[ct * 16 + lr];
    unsigned w01 = pkbf(rr[0] * (a[0] - mr[0] * uk) + vk,
                        rr[1] * (a[1] - mr[1] * uk) + vk);
    unsigned w23 = pkbf(rr[2] * (a[2] - mr[2] * uk) + vk,
                        rr[3] * (a[3] - mr[3] * uk) + vk);
    klds[lg * 4 + 0][ct * 16 + lr] = (unsigned short)w01;
    klds[lg * 4 + 1][ct * 16 + lr] = (unsigned short)(w01 >> 16);
    klds[lg * 4 + 2][ct * 16 + lr] = (unsigned short)w23;
    klds[lg * 4 + 3][ct * 16 + lr] = (unsigned short)(w23 >> 16);
  }
  asm volatile("" ::: "memory");  // same-wave LDS RAW; DS in-order
  // coalesced kmat store: wave writes its 16 contiguous rows (4x 1KB insts)
  unsigned short* kdst = kmat + (rowbase + w * 16) * CDIM;
  #pragma unroll
  for (int i = 0; i < 4; ++i) {
    int row = i * 4 + (l >> 4), ch = (l & 15) * 8;
    short8 vv = *(const short8*)&klds[row][ch];
    *(short8*)(kdst + row * CDIM + ch) = vv;
  }
  __syncthreads();  // all klds reads done before vlds overwrites the union

  // v pass (swapped): D[cout][n], cout=ct*16+lg*4+r, n=lr (lane's own row stats)
  #pragma unroll
  for (int ct = 0; ct < 8; ++ct) {
    f32x4 a = {0.f, 0.f, 0.f, 0.f};
    #pragma unroll
    for (int kb = 0; kb < 4; ++kb) {
      short8 wf = *(const short8*)(wpk + (((8 + ct) * 4 + kb) * 64 + l) * 8);
      a = __builtin_amdgcn_mfma_f32_16x16x32_bf16(wf, af[kb], a, 0, 0, 0);
    }
    f32x4 u4 = *(const f32x4*)(uvec + 128 + ct * 16 + lg * 4);
    f32x4 v4 = *(const f32x4*)(vvec + 128 + ct * 16 + lg * 4);
    unsigned w01 = pkbf(rstd * (a[0] - mean * u4[0]) + v4[0],
                        rstd * (a[1] - mean * u4[1]) + v4[1]);
    unsigned w23 = pkbf(rstd * (a[2] - mean * u4[2]) + v4[2],
                        rstd * (a[3] - mean * u4[3]) + v4[3]);
    vlds[ct * 16 + lg * 4 + 0][w * 16 + lr] = (unsigned short)w01;
    vlds[ct * 16 + lg * 4 + 1][w * 16 + lr] = (unsigned short)(w01 >> 16);
    vlds[ct * 16 + lg * 4 + 2][w * 16 + lr] = (unsigned short)w23;
    vlds[ct * 16 + lg * 4 + 3][w * 16 + lr] = (unsigned short)(w23 >> 16);
  }
  __syncthreads();
  // coalesced vT store: 128B-contiguous per c-row, 8 c-rows per inst
  unsigned short* vTb = vT + b * (CDIM * (long)NTOT) + (rowbase & 16383);
  #pragma unroll
  for (int i = 0; i < 4; ++i) {
    int c = i * 32 + (t >> 3), n8 = (t & 7) * 8;
    short8 vv = *(const short8*)&vlds[c][n8];
    *(short8*)(vTb + (long)c * NTOT + n8) = vv;
  }
}

// ---- Kq: q = (LN_s(slots) @ Wq) / sqrt(C) -> bf16 (initial iteration) ----
__global__ __launch_bounds__(512) void kq_init(
    const float* __restrict__ slots, const float* __restrict__ lnsg,
    const float* __restrict__ lnsb, const float* __restrict__ Wq,
    unsigned short* __restrict__ qout) {
  const int b = blockIdx.x, t = threadIdx.x;
  const int s = t >> 5, jq = (t & 31) * 4;
  __shared__ __align__(16) float lnq[2048];
  f32x4 x4 = *(const f32x4*)(slots + b * 2048 + t * 4);
  float ps = x4[0] + x4[1] + x4[2] + x4[3];
  float pq = x4[0]*x4[0] + x4[1]*x4[1] + x4[2]*x4[2] + x4[3]*x4[3];
  ps += __shfl_xor(ps, 1); ps += __shfl_xor(ps, 2); ps += __shfl_xor(ps, 4); ps += __shfl_xor(ps, 8); ps += __shfl_xor(ps, 16);
  pq += __shfl_xor(pq, 1); pq += __shfl_xor(pq, 2); pq += __shfl_xor(pq, 4); pq += __shfl_xor(pq, 8); pq += __shfl_xor(pq, 16);
  float mean = ps * (1.f / 128.f);
  float var  = pq * (1.f / 128.f) - mean * mean;
  float rstd = rsqrtf(var + 1e-5f);
  f32x4 l4 = (x4 - mean) * rstd * (*(const f32x4*)(lnsg + jq)) + (*(const f32x4*)(lnsb + jq));
  *(f32x4*)(lnq + t * 4) = l4;
  __syncthreads();
  f32x4 qa = {0.f, 0.f, 0.f, 0.f};
  const float* wqp = Wq + jq;
  const float* qrow = lnq + s * 128;
  for (int c = 0; c < 128; ++c)
    qa += *(const f32x4*)(wqp + c * 128) * qrow[c];
  qa *= 0.08838834764831845f;  // 1/sqrt(128)
  u32x2 pk = { pkbf(qa[0], qa[1]), pkbf(qa[2], qa[3]) };
  *(u32x2*)(qout + b * 2048 + t * 4) = pk;
}

// ---- K2: dots D[s][n] -> in-reg softmax -> LDS p-transpose (dbuf) -> PV ----
__global__ __launch_bounds__(256, 4) void k2_attn(
    const unsigned short* __restrict__ kmat, const unsigned short* __restrict__ vT,
    const unsigned short* __restrict__ qm,
    float* __restrict__ nump, float* __restrict__ denp) {
  const int nb = blockIdx.x, b = blockIdx.y;
  const int t = threadIdx.x, w = t >> 6, l = t & 63, lr = l & 15, lg = l >> 4;
  __shared__ unsigned short pbuf[4][2][16][40];  // per-wave, per-it double buffer
  __shared__ __align__(16) float redbuf[2][2048];
  __shared__ float denbuf[2][16];

  const unsigned short* kb_ = kmat + (long)b * (NTOT * CDIM);
  const unsigned short* vb  = vT + (long)b * (CDIM * (long)NTOT);
  const unsigned short* qb  = qm + b * (16 * CDIM);

  short8 qf[4];
  #pragma unroll
  for (int kk = 0; kk < 4; ++kk)
    qf[kk] = *(const short8*)(qb + lr * CDIM + kk * 32 + lg * 8);

  f32x4 acc[8];
  #pragma unroll
  for (int i = 0; i < 8; ++i) acc[i] = (f32x4){0.f, 0.f, 0.f, 0.f};
  f32x4 dacc = {0.f, 0.f, 0.f, 0.f};  // den per s=lg*4+r, own n=lr

  #pragma unroll
  for (int it = 0; it < 2; ++it) {
    const int n0 = nb * 256 + (it * 4 + w) * 32;
    #pragma unroll
    for (int h = 0; h < 2; ++h) {
      f32x4 d = {0.f, 0.f, 0.f, 0.f};
      const unsigned short* krow = kb_ + (n0 + h * 16 + lr) * CDIM + lg * 8;
      #pragma unroll
      for (int kk = 0; kk < 4; ++kk) {
        short8 kf = *(const short8*)(krow + kk * 32);
        d = __builtin_amdgcn_mfma_f32_16x16x32_bf16(qf[kk], kf, d, 0, 0, 0);  // D[s][n]
      }
      float e0 = __expf(d[0]), e1 = __expf(d[1]), e2 = __expf(d[2]), e3 = __expf(d[3]);
      float cs = e0 + e1 + e2 + e3;            // sum over s: 4 regs in-lane...
      cs += __shfl_xor(cs, 16);                // ...then over lg groups
      cs += __shfl_xor(cs, 32);
      float inv = 1.f / cs;
      float p0 = e0 * inv + 1e-8f, p1 = e1 * inv + 1e-8f,
            p2 = e2 * inv + 1e-8f, p3 = e3 * inv + 1e-8f;
      dacc[0] += p0; dacc[1] += p1; dacc[2] += p2; dacc[3] += p3;
      unsigned w01 = pkbf(p0, p1), w23 = pkbf(p2, p3);
      pbuf[w][it][lg * 4 + 0][h * 16 + lr] = (unsigned short)w01;
      pbuf[w][it][lg * 4 + 1][h * 16 + lr] = (unsigned short)(w01 >> 16);
      pbuf[w][it][lg * 4 + 2][h * 16 + lr] = (unsigned short)w23;
      pbuf[w][it][lg * 4 + 3][h * 16 + lr] = (unsigned short)(w23 >> 16);
    }
    // compiler orders may-aliasing LDS write->read; no fence needed
    short8 pf = *(const short8*)&pbuf[w][it][lr][lg * 8];  // B-frag: col=s=lr, k=n
    #pragma unroll
    for (int ct = 0; ct < 8; ++ct) {
      const unsigned short* vrow = vb + (ct * 16 + lr) * NTOT + n0 + lg * 8;
      short8 vf = *(const short8*)vrow;
      acc[ct] = __builtin_amdgcn_mfma_f32_16x16x32_bf16(vf, pf, acc[ct], 0, 0, 0);
    }
  }

  // den: reduce over n (lr lanes); all lanes end with den for s=lg*4+r
  #pragma unroll
  for (int m = 1; m <= 8; m <<= 1) {
    dacc[0] += __shfl_xor(dacc[0], m); dacc[1] += __shfl_xor(dacc[1], m);
    dacc[2] += __shfl_xor(dacc[2], m); dacc[3] += __shfl_xor(dacc[3], m);
  }

  if (w >= 2) {
    float* rw_ = &redbuf[w - 2][0];
    #pragma unroll
    for (int ct = 0; ct < 8; ++ct)
      *(f32x4*)(rw_ + lr * 128 + ct * 16 + lg * 4) = acc[ct];
    if (lr == 0) {
      #pragma unroll
      for (int r = 0; r < 4; ++r) denbuf[w - 2][lg * 4 + r] = dacc[r];
    }
  }
  __syncthreads();
  if (w < 2) {
    const float* rw_ = &redbuf[w][0];
    float* outp = nump + (((long)b * 64 + nb) * 2 + w) * 2048;
    #pragma unroll
    for (int ct = 0; ct < 8; ++ct) {
      f32x4 other = *(const f32x4*)(rw_ + lr * 128 + ct * 16 + lg * 4);
      *(f32x4*)(outp + lr * 128 + ct * 16 + lg * 4) = acc[ct] + other;
    }
    if (lr == 0) {
      #pragma unroll
      for (int r = 0; r < 4; ++r)
        denp[(((long)b * 64 + nb) * 2 + w) * 16 + lg * 4 + r] =
            dacc[r] + denbuf[w][lg * 4 + r];
    }
  }
}

// ---- K3: reduce partials+den -> updates -> GRU -> MLP -> slots (+ q next) ----
__global__ __launch_bounds__(128) void k3_update(
    const float* __restrict__ sprev, const float* __restrict__ nump,
    const float* __restrict__ denp,
    const float* __restrict__ wih, const float* __restrict__ whh,
    const float* __restrict__ bih, const float* __restrict__ bhh,
    const float* __restrict__ w1, const float* __restrict__ b1,
    const float* __restrict__ w2, const float* __restrict__ b2,
    const float* __restrict__ lnfg, const float* __restrict__ lnfb,
    const float* __restrict__ lnsg, const float* __restrict__ lnsb,
    const float* __restrict__ Wq,
    float* __restrict__ sout, unsigned short* __restrict__ qout, const int doq) {
  const int g = blockIdx.x, b = blockIdx.y, t = threadIdx.x;
  const int sl = t >> 5, jq = (t & 31) * 4;
  const int s = g * 4 + sl;
  const long base = (long)b * 2048 + g * 512;
  __shared__ __align__(16) float sp[512];
  __shared__ __align__(16) float upd[512];
  __shared__ __align__(16) float lnb[512];
  __shared__ __align__(16) float denred[2][4];

  f32x4 dv = *(const f32x4*)(denp + ((long)b * 128 + t) * 16 + g * 4);
  #pragma unroll
  for (int m = 1; m <= 32; m <<= 1) {
    dv[0] += __shfl_xor(dv[0], m); dv[1] += __shfl_xor(dv[1], m);
    dv[2] += __shfl_xor(dv[2], m); dv[3] += __shfl_xor(dv[3], m);
  }
  if ((t & 63) == 0) *(f32x4*)denred[t >> 6] = dv;

  f32x4 hp4 = *(const f32x4*)(sprev + base + t * 4);
  *(f32x4*)(sp + t * 4) = hp4;

  f32x4 ns = {0.f, 0.f, 0.f, 0.f};
  const float* np = nump + (long)b * 262144 + s * 128 + jq;
  #pragma unroll 4
  for (int p = 0; p < 128; ++p) ns += *(const f32x4*)(np + (long)p * 2048);
  __syncthreads();
  float den_s = denred[0][sl] + denred[1][sl];
  f32x4 u4 = ns * (1.f / den_s);
  *(f32x4*)(upd + t * 4) = u4;
  __syncthreads();

  f32x4 ir = {0,0,0,0}, iz = {0,0,0,0}, inn = {0,0,0,0};
  f32x4 hr = {0,0,0,0}, hz = {0,0,0,0}, hn = {0,0,0,0};
  const float* wih_p = wih + jq;
  const float* whh_p = whh + jq;
  const float* ur  = upd + sl * 128;
  const float* hrw = sp + sl * 128;
  for (int c = 0; c < 128; ++c) {
    float u = ur[c], h = hrw[c];
    ir  += *(const f32x4*)(wih_p + c * 384)       * u;
    iz  += *(const f32x4*)(wih_p + c * 384 + 128) * u;
    inn += *(const f32x4*)(wih_p + c * 384 + 256) * u;
    hr  += *(const f32x4*)(whh_p + c * 384)       * h;
    hz  += *(const f32x4*)(whh_p + c * 384 + 128) * h;
    hn  += *(const f32x4*)(whh_p + c * 384 + 256) * h;
  }
  ir  += *(const f32x4*)(bih + jq);
  iz  += *(const f32x4*)(bih + 128 + jq);
  inn += *(const f32x4*)(bih + 256 + jq);
  hr  += *(const f32x4*)(bhh + jq);
  hz  += *(const f32x4*)(bhh + 128 + jq);
  hn  += *(const f32x4*)(bhh + 256 + jq);
  f32x4 snew;
  #pragma unroll
  for (int i = 0; i < 4; ++i) {
    float r = sigf(ir[i] + hr[i]);
    float z = sigf(iz[i] + hz[i]);
    float n = tanhfast(inn[i] + r * hn[i]);
    snew[i] = (1.f - z) * n + z * hp4[i];
  }

  float ps = snew[0] + snew[1] + snew[2] + snew[3];
  float pq = snew[0]*snew[0] + snew[1]*snew[1] + snew[2]*snew[2] + snew[3]*snew[3];
  ps += __shfl_xor(ps, 1); ps += __shfl_xor(ps, 2); ps += __shfl_xor(ps, 4); ps += __shfl_xor(ps, 8); ps += __shfl_xor(ps, 16);
  pq += __shfl_xor(pq, 1); pq += __shfl_xor(pq, 2); pq += __shfl_xor(pq, 4); pq += __shfl_xor(pq, 8); pq += __shfl_xor(pq, 16);
  float mean = ps * (1.f / 128.f);
  float var  = pq * (1.f / 128.f) - mean * mean;
  float rstd = rsqrtf(var + 1e-5f);
  f32x4 lf = (snew - mean) * rstd * (*(const f32x4*)(lnfg + jq)) + (*(const f32x4*)(lnfb + jq));
  *(f32x4*)(lnb + t * 4) = lf;
  __syncthreads();

  f32x4 ha = {0,0,0,0};
  const float* w1p = w1 + jq;
  const float* lrow = lnb + sl * 128;
  for (int c = 0; c < 128; ++c)
    ha += *(const f32x4*)(w1p + c * 128) * lrow[c];
  ha += *(const f32x4*)(b1 + jq);
  #pragma unroll
  for (int i = 0; i < 4; ++i) ha[i] = fmaxf(ha[i], 0.f);
  *(f32x4*)(upd + t * 4) = ha;
  __syncthreads();

  f32x4 oa = {0,0,0,0};
  const float* w2p = w2 + jq;
  const float* hrow = upd + sl * 128;
  for (int c = 0; c < 128; ++c)
    oa += *(const f32x4*)(w2p + c * 128) * hrow[c];
  oa += *(const f32x4*)(b2 + jq);
  f32x4 sf = snew + oa;
  *(f32x4*)(sout + base + t * 4) = sf;

  if (doq) {
    float qs = sf[0] + sf[1] + sf[2] + sf[3];
    float qz = sf[0]*sf[0] + sf[1]*sf[1] + sf[2]*sf[2] + sf[3]*sf[3];
    qs += __shfl_xor(qs, 1); qs += __shfl_xor(qs, 2); qs += __shfl_xor(qs, 4); qs += __shfl_xor(qs, 8); qs += __shfl_xor(qs, 16);
    qz += __shfl_xor(qz, 1); qz += __shfl_xor(qz, 2); qz += __shfl_xor(qz, 4); qz += __shfl_xor(qz, 8); qz += __shfl_xor(qz, 16);
    float m2 = qs * (1.f / 128.f);
    float v2 = qz * (1.f / 128.f) - m2 * m2;
    float rs2 = rsqrtf(v2 + 1e-5f);
    f32x4 lq = (sf - m2) * rs2 * (*(const f32x4*)(lnsg + jq)) + (*(const f32x4*)(lnsb + jq));
    *(f32x4*)(sp + t * 4) = lq;
    __syncthreads();
    f32x4 qa = {0,0,0,0};
    const float* wqp = Wq + jq;
    const float* qrow = sp + sl * 128;
    for (int c = 0; c < 128; ++c)
      qa += *(const f32x4*)(wqp + c * 128) * qrow[c];
    qa *= 0.08838834764831845f;
    u32x2 pk = { pkbf(qa[0], qa[1]), pkbf(qa[2], qa[3]) };
    *(u32x2*)(qout + base + t * 4) = pk;
  }
}

extern "C" void kernel_launch(void* const* d_in, const int* in_sizes, int n_in,
                              void* d_out, int out_size, void* d_ws, size_t ws_size,
                              hipStream_t stream) {
  (void)in_sizes; (void)n_in; (void)out_size; (void)ws_size;
  const float* slots = (const float*)d_in[0];
  const float* inputs = (const float*)d_in[1];
  const float* Wq  = (const float*)d_in[2];
  const float* Wk  = (const float*)d_in[3];
  const float* Wv  = (const float*)d_in[4];
  const float* wih = (const float*)d_in[5];
  const float* whh = (const float*)d_in[6];
  const float* bih = (const float*)d_in[7];
  const float* bhh = (const float*)d_in[8];
  const float* w1  = (const float*)d_in[9];
  const float* b1  = (const float*)d_in[10];
  const float* w2  = (const float*)d_in[11];
  const float* b2  = (const float*)d_in[12];
  const float* lnig = (const float*)d_in[13];
  const float* lnib = (const float*)d_in[14];
  const float* lnsg = (const float*)d_in[15];
  const float* lnsb = (const float*)d_in[16];
  const float* lnfg = (const float*)d_in[17];
  const float* lnfb = (const float*)d_in[18];

  char* ws = (char*)d_ws;
  unsigned short* kmat = (unsigned short*)(ws);
  unsigned short* vT   = (unsigned short*)(ws + 134217728L);
  unsigned short* qbuf = (unsigned short*)(ws + 268435456L);
  unsigned short* wpk  = (unsigned short*)(ws + 268566528L);
  float* uvec = (float*)(ws + 268632064L);
  float* vvec = (float*)(ws + 268633088L);
  float* nump = (float*)(ws + 268634112L);
  float* denp = (float*)(ws + 302188544L);
  float* sbuf = (float*)(ws + 302450688L);

  k0_prep<<<1, 256, 0, stream>>>(Wk, Wv, lnig, lnib, wpk, uvec, vvec);
  k1_lnkv<<<8192, 256, 0, stream>>>(inputs, wpk, uvec, vvec, kmat, vT);
  kq_init<<<32, 512, 0, stream>>>(slots, lnsg, lnsb, Wq, qbuf);
  for (int it = 0; it < 3; ++it) {
    k2_attn<<<dim3(64, 32), 256, 0, stream>>>(kmat, vT, qbuf, nump, denp);
    const float* sprev = (it == 0) ? slots : sbuf;
    float* sdst = (it == 2) ? (float*)d_out : sbuf;
    k3_update<<<dim3(4, 32), 128, 0, stream>>>(sprev, nump, denp, wih, whh, bih, bhh,
                                      w1, b1, w2, b2, lnfg, lnfb, lnsg, lnsb, Wq,
                                      sdst, qbuf, (it < 2) ? 1 : 0);
  }
}

// Round 7
// 481.640 us; speedup vs baseline: 1.3992x; 1.1710x over previous
//
#include <hip/hip_runtime.h>

// SlotAttention MI355X implementation, v7.
// Changes vs v6: (1) k1 stages weights in LDS (32KB per pass) and feeds MFMA
// from ds_read -> per-wave VMEM count drops ~80 -> ~30 (the 64 per-wave L2
// fragment loads were the suspected issue-rate/latency cap); (2) k2 does 4
// n-tiles per wave (grid 32x32), halving partial traffic; (3) k0 parallelized.
// Workspace (~286 MiB): see kernel_launch.

#define NTOT 16384
#define CDIM 128

using short8 = __attribute__((ext_vector_type(8))) short;
using f32x4  = __attribute__((ext_vector_type(4))) float;
using u32x2  = __attribute__((ext_vector_type(2))) unsigned;

__device__ __forceinline__ unsigned pkbf(float lo, float hi) {
  unsigned r;
  asm("v_cvt_pk_bf16_f32 %0, %1, %2" : "=v"(r) : "v"(lo), "v"(hi));
  return r;
}
__device__ __forceinline__ unsigned short f2bf(float x) {
  union { float f; unsigned u; } v; v.f = x;
  unsigned r = v.u + 0x7FFFu + ((v.u >> 16) & 1u);
  return (unsigned short)(r >> 16);
}
__device__ __forceinline__ float sigf(float x) { return 1.f / (1.f + __expf(-x)); }
__device__ __forceinline__ float tanhfast(float x) {
  x = fminf(fmaxf(x, -15.f), 15.f);
  float e = __expf(2.f * x);
  return (e - 1.f) / (e + 1.f);
}

// ---- K0a: W' = diag(g)W packed to MFMA fragment order (128 blocks) ----
__global__ __launch_bounds__(256) void k0_prep(const float* __restrict__ Wk,
    const float* __restrict__ Wv, const float* __restrict__ g,
    unsigned short* __restrict__ wpk) {
  int idx = blockIdx.x * 256 + threadIdx.x;  // 0..32767
  int j = idx & 7, lane = (idx >> 3) & 63, kb = (idx >> 9) & 3,
      ct = (idx >> 11) & 7, which = idx >> 14;
  int lr = lane & 15, lg = lane >> 4;
  int cin = kb * 32 + lg * 8 + j, cout = ct * 16 + lr;
  const float* W = which ? Wv : Wk;
  wpk[idx] = f2bf(g[cin] * W[cin * 128 + cout]);
}

// ---- K0b: u = colsum(g*W), v = b@W ----
__global__ void k0_uv(const float* __restrict__ Wk, const float* __restrict__ Wv,
                      const float* __restrict__ g, const float* __restrict__ bb,
                      float* __restrict__ uvec, float* __restrict__ vvec) {
  const int t = threadIdx.x;              // 256 threads, 1 block
  const int which = t >> 7, cout = t & 127;
  const float* W = which ? Wv : Wk;
  float u = 0.f, v = 0.f;
  for (int cin = 0; cin < 128; ++cin) {
    float wv = W[cin * 128 + cout];
    u += g[cin] * wv;
    v += bb[cin] * wv;
  }
  uvec[t] = u;
  vvec[t] = v;
}

// ---- K1: x -> stats -> MFMA vs LDS-staged W' -> affine -> bounce -> stores ----
__global__ __launch_bounds__(256, 3) void k1_lnkv(
    const float* __restrict__ in, const unsigned short* __restrict__ wpk,
    const float* __restrict__ uvec, const float* __restrict__ vvec,
    unsigned short* __restrict__ kmat, unsigned short* __restrict__ vT) {
  __shared__ __align__(16) unsigned short wlds[16384];  // 32 KB staged weights
  // union: phase A = klds (per-wave [16][132] ushort), phase B = vlds [128][68]
  __shared__ __align__(16) char smem[17408];
  const int t = threadIdx.x, w = t >> 6, l = t & 63, lr = l & 15, lg = l >> 4;
  unsigned short (*klds)[132] = (unsigned short(*)[132])(smem + w * 4224);
  unsigned short (*vlds)[68]  = (unsigned short(*)[68])smem;
  const long rowbase = (long)blockIdx.x * 64;
  const long b = rowbase >> 14;

  // stage k-pass weights (32 KB, contiguous)
  #pragma unroll
  for (int i = 0; i < 8; ++i) {
    int idx = t + i * 256;
    *(short8*)(wlds + idx * 8) = *(const short8*)(wpk + idx * 8);
  }

  // fragment-order loads: lane holds row (w*16+lr), cols kb*32+lg*8..+7
  const float* src = in + (rowbase + w * 16 + lr) * CDIM;
  f32x4 x[4][2];
  #pragma unroll
  for (int kb = 0; kb < 4; ++kb) {
    x[kb][0] = *(const f32x4*)(src + kb * 32 + lg * 8);
    x[kb][1] = *(const f32x4*)(src + kb * 32 + lg * 8 + 4);
  }
  float s1 = 0.f, s2 = 0.f;
  #pragma unroll
  for (int kb = 0; kb < 4; ++kb)
    #pragma unroll
    for (int h = 0; h < 2; ++h)
      #pragma unroll
      for (int i = 0; i < 4; ++i) { float xx = x[kb][h][i]; s1 += xx; s2 += xx * xx; }
  s1 += __shfl_xor(s1, 16); s1 += __shfl_xor(s1, 32);
  s2 += __shfl_xor(s2, 16); s2 += __shfl_xor(s2, 32);
  const float mean = s1 * (1.f / 128.f);
  const float rstd = rsqrtf(s2 * (1.f / 128.f) - mean * mean + 1e-5f);

  short8 af[4];
  #pragma unroll
  for (int kb = 0; kb < 4; ++kb) {
    union { unsigned uw[4]; short8 s8; } c;
    c.uw[0] = pkbf(x[kb][0][0], x[kb][0][1]);
    c.uw[1] = pkbf(x[kb][0][2], x[kb][0][3]);
    c.uw[2] = pkbf(x[kb][1][0], x[kb][1][1]);
    c.uw[3] = pkbf(x[kb][1][2], x[kb][1][3]);
    af[kb] = c.s8;
  }
  // stats broadcast to D rows n = lg*4+r
  float mr[4], rr[4];
  #pragma unroll
  for (int r = 0; r < 4; ++r) {
    mr[r] = __shfl(mean, lg * 4 + r);
    rr[r] = __shfl(rstd, lg * 4 + r);
  }
  __syncthreads();  // #1: k-weights staged

  // k pass: D[n][cout], n=lg*4+r, cout=ct*16+lr
  #pragma unroll
  for (int ct = 0; ct < 8; ++ct) {
    f32x4 a = {0.f, 0.f, 0.f, 0.f};
    #pragma unroll
    for (int kb = 0; kb < 4; ++kb) {
      short8 wf = *(const short8*)(wlds + ((ct * 4 + kb) * 64 + l) * 8);
      a = __builtin_amdgcn_mfma_f32_16x16x32_bf16(af[kb], wf, a, 0, 0, 0);
    }
    float uk = uvec[ct * 16 + lr], vk = vvec[ct * 16 + lr];
    unsigned w01 = pkbf(rr[0] * (a[0] - mr[0] * uk) + vk,
                        rr[1] * (a[1] - mr[1] * uk) + vk);
    unsigned w23 = pkbf(rr[2] * (a[2] - mr[2] * uk) + vk,
                        rr[3] * (a[3] - mr[3] * uk) + vk);
    klds[lg * 4 + 0][ct * 16 + lr] = (unsigned short)w01;
    klds[lg * 4 + 1][ct * 16 + lr] = (unsigned short)(w01 >> 16);
    klds[lg * 4 + 2][ct * 16 + lr] = (unsigned short)w23;
    klds[lg * 4 + 3][ct * 16 + lr] = (unsigned short)(w23 >> 16);
  }
  asm volatile("" ::: "memory");  // same-wave LDS RAW; DS in-order
  // coalesced kmat store: wave writes its 16 contiguous rows
  unsigned short* kdst = kmat + (rowbase + w * 16) * CDIM;
  #pragma unroll
  for (int i = 0; i < 4; ++i) {
    int row = i * 4 + (l >> 4), ch = (l & 15) * 8;
    short8 vv = *(const short8*)&klds[row][ch];
    *(short8*)(kdst + row * CDIM + ch) = vv;
  }
  __syncthreads();  // #2: all k-pass wlds reads done

  // stage v-pass weights
  #pragma unroll
  for (int i = 0; i < 8; ++i) {
    int idx = t + i * 256;
    *(short8*)(wlds + idx * 8) = *(const short8*)(wpk + 16384 + idx * 8);
  }
  __syncthreads();  // #3: v-weights staged; klds bounce reads done

  // v pass (swapped): D[cout][n], cout=ct*16+lg*4+r, n=lr (lane's own stats)
  #pragma unroll
  for (int ct = 0; ct < 8; ++ct) {
    f32x4 a = {0.f, 0.f, 0.f, 0.f};
    #pragma unroll
    for (int kb = 0; kb < 4; ++kb) {
      short8 wf = *(const short8*)(wlds + ((ct * 4 + kb) * 64 + l) * 8);
      a = __builtin_amdgcn_mfma_f32_16x16x32_bf16(wf, af[kb], a, 0, 0, 0);
    }
    f32x4 u4 = *(const f32x4*)(uvec + 128 + ct * 16 + lg * 4);
    f32x4 v4 = *(const f32x4*)(vvec + 128 + ct * 16 + lg * 4);
    unsigned w01 = pkbf(rstd * (a[0] - mean * u4[0]) + v4[0],
                        rstd * (a[1] - mean * u4[1]) + v4[1]);
    unsigned w23 = pkbf(rstd * (a[2] - mean * u4[2]) + v4[2],
                        rstd * (a[3] - mean * u4[3]) + v4[3]);
    vlds[ct * 16 + lg * 4 + 0][w * 16 + lr] = (unsigned short)w01;
    vlds[ct * 16 + lg * 4 + 1][w * 16 + lr] = (unsigned short)(w01 >> 16);
    vlds[ct * 16 + lg * 4 + 2][w * 16 + lr] = (unsigned short)w23;
    vlds[ct * 16 + lg * 4 + 3][w * 16 + lr] = (unsigned short)(w23 >> 16);
  }
  __syncthreads();  // #4: vlds complete
  // coalesced vT store: 128B-contiguous per c-row
  unsigned short* vTb = vT + b * (CDIM * (long)NTOT) + (rowbase & 16383);
  #pragma unroll
  for (int i = 0; i < 4; ++i) {
    int c = i * 32 + (t >> 3), n8 = (t & 7) * 8;
    short8 vv = *(const short8*)&vlds[c][n8];
    *(short8*)(vTb + (long)c * NTOT + n8) = vv;
  }
}

// ---- Kq: q = (LN_s(slots) @ Wq) / sqrt(C) -> bf16 (initial iteration) ----
__global__ __launch_bounds__(512) void kq_init(
    const float* __restrict__ slots, const float* __restrict__ lnsg,
    const float* __restrict__ lnsb, const float* __restrict__ Wq,
    unsigned short* __restrict__ qout) {
  const int b = blockIdx.x, t = threadIdx.x;
  const int s = t >> 5, jq = (t & 31) * 4;
  __shared__ __align__(16) float lnq[2048];
  f32x4 x4 = *(const f32x4*)(slots + b * 2048 + t * 4);
  float ps = x4[0] + x4[1] + x4[2] + x4[3];
  float pq = x4[0]*x4[0] + x4[1]*x4[1] + x4[2]*x4[2] + x4[3]*x4[3];
  ps += __shfl_xor(ps, 1); ps += __shfl_xor(ps, 2); ps += __shfl_xor(ps, 4); ps += __shfl_xor(ps, 8); ps += __shfl_xor(ps, 16);
  pq += __shfl_xor(pq, 1); pq += __shfl_xor(pq, 2); pq += __shfl_xor(pq, 4); pq += __shfl_xor(pq, 8); pq += __shfl_xor(pq, 16);
  float mean = ps * (1.f / 128.f);
  float var  = pq * (1.f / 128.f) - mean * mean;
  float rstd = rsqrtf(var + 1e-5f);
  f32x4 l4 = (x4 - mean) * rstd * (*(const f32x4*)(lnsg + jq)) + (*(const f32x4*)(lnsb + jq));
  *(f32x4*)(lnq + t * 4) = l4;
  __syncthreads();
  f32x4 qa = {0.f, 0.f, 0.f, 0.f};
  const float* wqp = Wq + jq;
  const float* qrow = lnq + s * 128;
  for (int c = 0; c < 128; ++c)
    qa += *(const f32x4*)(wqp + c * 128) * qrow[c];
  qa *= 0.08838834764831845f;  // 1/sqrt(128)
  u32x2 pk = { pkbf(qa[0], qa[1]), pkbf(qa[2], qa[3]) };
  *(u32x2*)(qout + b * 2048 + t * 4) = pk;
}

// ---- K2: dots D[s][n] -> in-reg softmax -> LDS p-transpose -> PV (4 tiles) ----
__global__ __launch_bounds__(256, 4) void k2_attn(
    const unsigned short* __restrict__ kmat, const unsigned short* __restrict__ vT,
    const unsigned short* __restrict__ qm,
    float* __restrict__ nump, float* __restrict__ denp) {
  const int nb = blockIdx.x, b = blockIdx.y;
  const int t = threadIdx.x, w = t >> 6, l = t & 63, lr = l & 15, lg = l >> 4;
  __shared__ unsigned short pbuf[4][4][16][40];  // per-wave, per-it buffers
  __shared__ __align__(16) float redbuf[2][2048];
  __shared__ float denbuf[2][16];

  const unsigned short* kb_ = kmat + (long)b * (NTOT * CDIM);
  const unsigned short* vb  = vT + (long)b * (CDIM * (long)NTOT);
  const unsigned short* qb  = qm + b * (16 * CDIM);

  short8 qf[4];
  #pragma unroll
  for (int kk = 0; kk < 4; ++kk)
    qf[kk] = *(const short8*)(qb + lr * CDIM + kk * 32 + lg * 8);

  f32x4 acc[8];
  #pragma unroll
  for (int i = 0; i < 8; ++i) acc[i] = (f32x4){0.f, 0.f, 0.f, 0.f};
  f32x4 dacc = {0.f, 0.f, 0.f, 0.f};  // den per s=lg*4+r, own n=lr

  #pragma unroll
  for (int it = 0; it < 4; ++it) {
    const int n0 = nb * 512 + (it * 4 + w) * 32;
    #pragma unroll
    for (int h = 0; h < 2; ++h) {
      f32x4 d = {0.f, 0.f, 0.f, 0.f};
      const unsigned short* krow = kb_ + (n0 + h * 16 + lr) * CDIM + lg * 8;
      #pragma unroll
      for (int kk = 0; kk < 4; ++kk) {
        short8 kf = *(const short8*)(krow + kk * 32);
        d = __builtin_amdgcn_mfma_f32_16x16x32_bf16(qf[kk], kf, d, 0, 0, 0);  // D[s][n]
      }
      float e0 = __expf(d[0]), e1 = __expf(d[1]), e2 = __expf(d[2]), e3 = __expf(d[3]);
      float cs = e0 + e1 + e2 + e3;            // sum over s: 4 regs in-lane...
      cs += __shfl_xor(cs, 16);                // ...then over lg groups
      cs += __shfl_xor(cs, 32);
      float inv = 1.f / cs;
      float p0 = e0 * inv + 1e-8f, p1 = e1 * inv + 1e-8f,
            p2 = e2 * inv + 1e-8f, p3 = e3 * inv + 1e-8f;
      dacc[0] += p0; dacc[1] += p1; dacc[2] += p2; dacc[3] += p3;
      unsigned w01 = pkbf(p0, p1), w23 = pkbf(p2, p3);
      pbuf[w][it][lg * 4 + 0][h * 16 + lr] = (unsigned short)w01;
      pbuf[w][it][lg * 4 + 1][h * 16 + lr] = (unsigned short)(w01 >> 16);
      pbuf[w][it][lg * 4 + 2][h * 16 + lr] = (unsigned short)w23;
      pbuf[w][it][lg * 4 + 3][h * 16 + lr] = (unsigned short)(w23 >> 16);
    }
    short8 pf = *(const short8*)&pbuf[w][it][lr][lg * 8];  // B-frag: col=s=lr, k=n
    #pragma unroll
    for (int ct = 0; ct < 8; ++ct) {
      const unsigned short* vrow = vb + (ct * 16 + lr) * NTOT + n0 + lg * 8;
      short8 vf = *(const short8*)vrow;
      acc[ct] = __builtin_amdgcn_mfma_f32_16x16x32_bf16(vf, pf, acc[ct], 0, 0, 0);
    }
  }

  // den: reduce over n (lr lanes); all lanes end with den for s=lg*4+r
  #pragma unroll
  for (int m = 1; m <= 8; m <<= 1) {
    dacc[0] += __shfl_xor(dacc[0], m); dacc[1] += __shfl_xor(dacc[1], m);
    dacc[2] += __shfl_xor(dacc[2], m); dacc[3] += __shfl_xor(dacc[3], m);
  }

  if (w >= 2) {
    float* rw_ = &redbuf[w - 2][0];
    #pragma unroll
    for (int ct = 0; ct < 8; ++ct)
      *(f32x4*)(rw_ + lr * 128 + ct * 16 + lg * 4) = acc[ct];
    if (lr == 0) {
      #pragma unroll
      for (int r = 0; r < 4; ++r) denbuf[w - 2][lg * 4 + r] = dacc[r];
    }
  }
  __syncthreads();
  if (w < 2) {
    const float* rw_ = &redbuf[w][0];
    float* outp = nump + (((long)b * 32 + nb) * 2 + w) * 2048;
    #pragma unroll
    for (int ct = 0; ct < 8; ++ct) {
      f32x4 other = *(const f32x4*)(rw_ + lr * 128 + ct * 16 + lg * 4);
      *(f32x4*)(outp + lr * 128 + ct * 16 + lg * 4) = acc[ct] + other;
    }
    if (lr == 0) {
      #pragma unroll
      for (int r = 0; r < 4; ++r)
        denp[(((long)b * 32 + nb) * 2 + w) * 16 + lg * 4 + r] =
            dacc[r] + denbuf[w][lg * 4 + r];
    }
  }
}

// ---- K3: reduce partials+den -> updates -> GRU -> MLP -> slots (+ q next) ----
__global__ __launch_bounds__(128) void k3_update(
    const float* __restrict__ sprev, const float* __restrict__ nump,
    const float* __restrict__ denp,
    const float* __restrict__ wih, const float* __restrict__ whh,
    const float* __restrict__ bih, const float* __restrict__ bhh,
    const float* __restrict__ w1, const float* __restrict__ b1,
    const float* __restrict__ w2, const float* __restrict__ b2,
    const float* __restrict__ lnfg, const float* __restrict__ lnfb,
    const float* __restrict__ lnsg, const float* __restrict__ lnsb,
    const float* __restrict__ Wq,
    float* __restrict__ sout, unsigned short* __restrict__ qout, const int doq) {
  const int g = blockIdx.x, b = blockIdx.y, t = threadIdx.x;
  const int sl = t >> 5, jq = (t & 31) * 4;
  const int s = g * 4 + sl;
  const long base = (long)b * 2048 + g * 512;
  __shared__ __align__(16) float sp[512];
  __shared__ __align__(16) float upd[512];
  __shared__ __align__(16) float lnb[512];
  __shared__ __align__(16) float denred[2][4];

  f32x4 dv = {0.f, 0.f, 0.f, 0.f};
  if (t < 64) dv = *(const f32x4*)(denp + ((long)b * 64 + t) * 16 + g * 4);
  #pragma unroll
  for (int m = 1; m <= 32; m <<= 1) {
    dv[0] += __shfl_xor(dv[0], m); dv[1] += __shfl_xor(dv[1], m);
    dv[2] += __shfl_xor(dv[2], m); dv[3] += __shfl_xor(dv[3], m);
  }
  if ((t & 63) == 0) *(f32x4*)denred[t >> 6] = dv;

  f32x4 hp4 = *(const f32x4*)(sprev + base + t * 4);
  *(f32x4*)(sp + t * 4) = hp4;

  f32x4 ns = {0.f, 0.f, 0.f, 0.f};
  const float* np = nump + (long)b * 131072 + s * 128 + jq;
  #pragma unroll 4
  for (int p = 0; p < 64; ++p) ns += *(const f32x4*)(np + (long)p * 2048);
  __syncthreads();
  float den_s = denred[0][sl] + denred[1][sl];
  f32x4 u4 = ns * (1.f / den_s);
  *(f32x4*)(upd + t * 4) = u4;
  __syncthreads();

  f32x4 ir = {0,0,0,0}, iz = {0,0,0,0}, inn = {0,0,0,0};
  f32x4 hr = {0,0,0,0}, hz = {0,0,0,0}, hn = {0,0,0,0};
  const float* wih_p = wih + jq;
  const float* whh_p = whh + jq;
  const float* ur  = upd + sl * 128;
  const float* hrw = sp + sl * 128;
  for (int c = 0; c < 128; ++c) {
    float u = ur[c], h = hrw[c];
    ir  += *(const f32x4*)(wih_p + c * 384)       * u;
    iz  += *(const f32x4*)(wih_p + c * 384 + 128) * u;
    inn += *(const f32x4*)(wih_p + c * 384 + 256) * u;
    hr  += *(const f32x4*)(whh_p + c * 384)       * h;
    hz  += *(const f32x4*)(whh_p + c * 384 + 128) * h;
    hn  += *(const f32x4*)(whh_p + c * 384 + 256) * h;
  }
  ir  += *(const f32x4*)(bih + jq);
  iz  += *(const f32x4*)(bih + 128 + jq);
  inn += *(const f32x4*)(bih + 256 + jq);
  hr  += *(const f32x4*)(bhh + jq);
  hz  += *(const f32x4*)(bhh + 128 + jq);
  hn  += *(const f32x4*)(bhh + 256 + jq);
  f32x4 snew;
  #pragma unroll
  for (int i = 0; i < 4; ++i) {
    float r = sigf(ir[i] + hr[i]);
    float z = sigf(iz[i] + hz[i]);
    float n = tanhfast(inn[i] + r * hn[i]);
    snew[i] = (1.f - z) * n + z * hp4[i];
  }

  float ps = snew[0] + snew[1] + snew[2] + snew[3];
  float pq = snew[0]*snew[0] + snew[1]*snew[1] + snew[2]*snew[2] + snew[3]*snew[3];
  ps += __shfl_xor(ps, 1); ps += __shfl_xor(ps, 2); ps += __shfl_xor(ps, 4); ps += __shfl_xor(ps, 8); ps += __shfl_xor(ps, 16);
  pq += __shfl_xor(pq, 1); pq += __shfl_xor(pq, 2); pq += __shfl_xor(pq, 4); pq += __shfl_xor(pq, 8); pq += __shfl_xor(pq, 16);
  float mean = ps * (1.f / 128.f);
  float var  = pq * (1.f / 128.f) - mean * mean;
  float rstd = rsqrtf(var + 1e-5f);
  f32x4 lf = (snew - mean) * rstd * (*(const f32x4*)(lnfg + jq)) + (*(const f32x4*)(lnfb + jq));
  *(f32x4*)(lnb + t * 4) = lf;
  __syncthreads();

  f32x4 ha = {0,0,0,0};
  const float* w1p = w1 + jq;
  const float* lrow = lnb + sl * 128;
  for (int c = 0; c < 128; ++c)
    ha += *(const f32x4*)(w1p + c * 128) * lrow[c];
  ha += *(const f32x4*)(b1 + jq);
  #pragma unroll
  for (int i = 0; i < 4; ++i) ha[i] = fmaxf(ha[i], 0.f);
  *(f32x4*)(upd + t * 4) = ha;
  __syncthreads();

  f32x4 oa = {0,0,0,0};
  const float* w2p = w2 + jq;
  const float* hrow = upd + sl * 128;
  for (int c = 0; c < 128; ++c)
    oa += *(const f32x4*)(w2p + c * 128) * hrow[c];
  oa += *(const f32x4*)(b2 + jq);
  f32x4 sf = snew + oa;
  *(f32x4*)(sout + base + t * 4) = sf;

  if (doq) {
    float qs = sf[0] + sf[1] + sf[2] + sf[3];
    float qz = sf[0]*sf[0] + sf[1]*sf[1] + sf[2]*sf[2] + sf[3]*sf[3];
    qs += __shfl_xor(qs, 1); qs += __shfl_xor(qs, 2); qs += __shfl_xor(qs, 4); qs += __shfl_xor(qs, 8); qs += __shfl_xor(qs, 16);
    qz += __shfl_xor(qz, 1); qz += __shfl_xor(qz, 2); qz += __shfl_xor(qz, 4); qz += __shfl_xor(qz, 8); qz += __shfl_xor(qz, 16);
    float m2 = qs * (1.f / 128.f);
    float v2 = qz * (1.f / 128.f) - m2 * m2;
    float rs2 = rsqrtf(v2 + 1e-5f);
    f32x4 lq = (sf - m2) * rs2 * (*(const f32x4*)(lnsg + jq)) + (*(const f32x4*)(lnsb + jq));
    *(f32x4*)(sp + t * 4) = lq;
    __syncthreads();
    f32x4 qa = {0,0,0,0};
    const float* wqp = Wq + jq;
    const float* qrow = sp + sl * 128;
    for (int c = 0; c < 128; ++c)
      qa += *(const f32x4*)(wqp + c * 128) * qrow[c];
    qa *= 0.08838834764831845f;
    u32x2 pk = { pkbf(qa[0], qa[1]), pkbf(qa[2], qa[3]) };
    *(u32x2*)(qout + base + t * 4) = pk;
  }
}

extern "C" void kernel_launch(void* const* d_in, const int* in_sizes, int n_in,
                              void* d_out, int out_size, void* d_ws, size_t ws_size,
                              hipStream_t stream) {
  (void)in_sizes; (void)n_in; (void)out_size; (void)ws_size;
  const float* slots = (const float*)d_in[0];
  const float* inputs = (const float*)d_in[1];
  const float* Wq  = (const float*)d_in[2];
  const float* Wk  = (const float*)d_in[3];
  const float* Wv  = (const float*)d_in[4];
  const float* wih = (const float*)d_in[5];
  const float* whh = (const float*)d_in[6];
  const float* bih = (const float*)d_in[7];
  const float* bhh = (const float*)d_in[8];
  const float* w1  = (const float*)d_in[9];
  const float* b1  = (const float*)d_in[10];
  const float* w2  = (const float*)d_in[11];
  const float* b2  = (const float*)d_in[12];
  const float* lnig = (const float*)d_in[13];
  const float* lnib = (const float*)d_in[14];
  const float* lnsg = (const float*)d_in[15];
  const float* lnsb = (const float*)d_in[16];
  const float* lnfg = (const float*)d_in[17];
  const float* lnfb = (const float*)d_in[18];

  char* ws = (char*)d_ws;
  unsigned short* kmat = (unsigned short*)(ws);
  unsigned short* vT   = (unsigned short*)(ws + 134217728L);
  unsigned short* qbuf = (unsigned short*)(ws + 268435456L);
  unsigned short* wpk  = (unsigned short*)(ws + 268566528L);
  float* uvec = (float*)(ws + 268632064L);
  float* vvec = (float*)(ws + 268633088L);
  float* nump = (float*)(ws + 268634112L);   // 32*64*2048*4 = 16.78 MB
  float* denp = (float*)(ws + 285411328L);   // 32*64*16*4
  float* sbuf = (float*)(ws + 285542400L);

  k0_prep<<<128, 256, 0, stream>>>(Wk, Wv, lnig, wpk);
  k0_uv<<<1, 256, 0, stream>>>(Wk, Wv, lnig, lnib, uvec, vvec);
  k1_lnkv<<<8192, 256, 0, stream>>>(inputs, wpk, uvec, vvec, kmat, vT);
  kq_init<<<32, 512, 0, stream>>>(slots, lnsg, lnsb, Wq, qbuf);
  for (int it = 0; it < 3; ++it) {
    k2_attn<<<dim3(32, 32), 256, 0, stream>>>(kmat, vT, qbuf, nump, denp);
    const float* sprev = (it == 0) ? slots : sbuf;
    float* sdst = (it == 2) ? (float*)d_out : sbuf;
    k3_update<<<dim3(4, 32), 128, 0, stream>>>(sprev, nump, denp, wih, whh, bih, bhh,
                                      w1, b1, w2, b2, lnfg, lnfb, lnsg, lnsb, Wq,
                                      sdst, qbuf, (it < 2) ? 1 : 0);
  }
}

// Round 9
// 367.966 us; speedup vs baseline: 1.8315x; 1.3089x over previous
//
#include <hip/hip_runtime.h>

// SlotAttention MI355X v9 — v8 with the k2 xT transpose stride bug fixed
// (byte strides were 2x: kk*4096+lg*1024+e*128 -> kk*2048+lg*512+e*64;
// OOB LDS writes were the NaN source).
// Algebra: dots = xln @ (Wqk·lnq^T)/scale with Wqk = Wq@Wk^T (precomputed);
// updates = (p@xln)/den @ Wv (Wv applied in f32 in k3). Only xln (134 MB)
// is materialized; each k2 iteration streams it once.
// Workspace (~168.5 MiB): xln@0, qbuf@134217728, wqk@134348800,
//   nump@134414336 (33.5MB), denp@167968768, sbuf@168230912.

#define NTOT 16384
#define CDIM 128

using short8 = __attribute__((ext_vector_type(8))) short;
using f32x4  = __attribute__((ext_vector_type(4))) float;
using u32x2  = __attribute__((ext_vector_type(2))) unsigned;

__device__ __forceinline__ unsigned pkbf(float lo, float hi) {
  unsigned r;
  asm("v_cvt_pk_bf16_f32 %0, %1, %2" : "=v"(r) : "v"(lo), "v"(hi));
  return r;
}
__device__ __forceinline__ float sigf(float x) { return 1.f / (1.f + __expf(-x)); }
__device__ __forceinline__ float tanhfast(float x) {
  x = fminf(fmaxf(x, -15.f), 15.f);
  float e = __expf(2.f * x);
  return (e - 1.f) / (e + 1.f);
}

// ---- K0: Wqk[cq][ck] = sum_c2 Wq[cq][c2] * Wk[ck][c2]  (= Wq @ Wk^T) ----
__global__ __launch_bounds__(256) void k0_wqk(const float* __restrict__ Wq,
    const float* __restrict__ Wk, float* __restrict__ wqk) {
  int idx = blockIdx.x * 256 + threadIdx.x;  // 16384
  int cq = idx >> 7, ck = idx & 127;
  const float* a = Wq + cq * 128;
  const float* b = Wk + ck * 128;
  float s = 0.f;
  #pragma unroll 8
  for (int i = 0; i < 128; i += 4) {
    f32x4 av = *(const f32x4*)(a + i), bv = *(const f32x4*)(b + i);
    s += av[0]*bv[0] + av[1]*bv[1] + av[2]*bv[2] + av[3]*bv[3];
  }
  wqk[idx] = s;
}

// ---- K1: pure LayerNorm stream: x f32 -> xln bf16 [b][n][c] row-major ----
__global__ __launch_bounds__(256) void k1_ln(const float* __restrict__ in,
    const float* __restrict__ gam, const float* __restrict__ bet,
    unsigned short* __restrict__ xln) {
  __shared__ __align__(16) unsigned short xb[64 * 136];  // pad 8 -> 272B rows
  __shared__ float gs[128], bs[128];
  const int t = threadIdx.x, w = t >> 6, l = t & 63, lr = l & 15, lg = l >> 4;
  if (t < 128) { gs[t] = gam[t]; bs[t] = bet[t]; }
  const long rowbase = (long)blockIdx.x * 64;
  const float* src = in + (rowbase + w * 16 + lr) * CDIM;
  f32x4 x[4][2];
  #pragma unroll
  for (int kb = 0; kb < 4; ++kb) {
    x[kb][0] = *(const f32x4*)(src + kb * 32 + lg * 8);
    x[kb][1] = *(const f32x4*)(src + kb * 32 + lg * 8 + 4);
  }
  float s1 = 0.f, s2 = 0.f;
  #pragma unroll
  for (int kb = 0; kb < 4; ++kb)
    #pragma unroll
    for (int h = 0; h < 2; ++h)
      #pragma unroll
      for (int i = 0; i < 4; ++i) { float xx = x[kb][h][i]; s1 += xx; s2 += xx * xx; }
  s1 += __shfl_xor(s1, 16); s1 += __shfl_xor(s1, 32);
  s2 += __shfl_xor(s2, 16); s2 += __shfl_xor(s2, 32);
  const float mean = s1 * (1.f / 128.f);
  const float rstd = rsqrtf(s2 * (1.f / 128.f) - mean * mean + 1e-5f);
  __syncthreads();  // gs/bs ready
  #pragma unroll
  for (int kb = 0; kb < 4; ++kb) {
    int c0 = kb * 32 + lg * 8;
    union { unsigned uw[4]; short8 s8; } cv;
    #pragma unroll
    for (int p = 0; p < 2; ++p) {
      float y0 = (x[kb][p][0] - mean) * rstd * gs[c0 + p*4 + 0] + bs[c0 + p*4 + 0];
      float y1 = (x[kb][p][1] - mean) * rstd * gs[c0 + p*4 + 1] + bs[c0 + p*4 + 1];
      float y2 = (x[kb][p][2] - mean) * rstd * gs[c0 + p*4 + 2] + bs[c0 + p*4 + 2];
      float y3 = (x[kb][p][3] - mean) * rstd * gs[c0 + p*4 + 3] + bs[c0 + p*4 + 3];
      cv.uw[p*2 + 0] = pkbf(y0, y1);
      cv.uw[p*2 + 1] = pkbf(y2, y3);
    }
    *(short8*)(xb + (w * 16 + lr) * 136 + c0) = cv.s8;
  }
  asm volatile("" ::: "memory");  // same-wave LDS RAW
  unsigned short* dst = xln + (rowbase + w * 16) * CDIM;
  #pragma unroll
  for (int i = 0; i < 4; ++i) {
    int row = i * 4 + (l >> 4), cb = (l & 15) * 8;
    short8 v = *(const short8*)(xb + (w * 16 + row) * 136 + cb);
    *(short8*)(dst + row * CDIM + cb) = v;  // 1KB contiguous per instr
  }
}

// ---- Kq: qa = (LN_s(slots) @ Wqk) / sqrt(C) -> bf16 [b][16][128] ----
__global__ __launch_bounds__(512) void kq_init(
    const float* __restrict__ slots, const float* __restrict__ lnsg,
    const float* __restrict__ lnsb, const float* __restrict__ wqk,
    unsigned short* __restrict__ qout) {
  const int b = blockIdx.x, t = threadIdx.x;
  const int s = t >> 5, jq = (t & 31) * 4;
  __shared__ __align__(16) float lnq[2048];
  f32x4 x4 = *(const f32x4*)(slots + b * 2048 + t * 4);
  float ps = x4[0] + x4[1] + x4[2] + x4[3];
  float pq = x4[0]*x4[0] + x4[1]*x4[1] + x4[2]*x4[2] + x4[3]*x4[3];
  ps += __shfl_xor(ps, 1); ps += __shfl_xor(ps, 2); ps += __shfl_xor(ps, 4); ps += __shfl_xor(ps, 8); ps += __shfl_xor(ps, 16);
  pq += __shfl_xor(pq, 1); pq += __shfl_xor(pq, 2); pq += __shfl_xor(pq, 4); pq += __shfl_xor(pq, 8); pq += __shfl_xor(pq, 16);
  float mean = ps * (1.f / 128.f);
  float var  = pq * (1.f / 128.f) - mean * mean;
  float rstd = rsqrtf(var + 1e-5f);
  f32x4 l4 = (x4 - mean) * rstd * (*(const f32x4*)(lnsg + jq)) + (*(const f32x4*)(lnsb + jq));
  *(f32x4*)(lnq + t * 4) = l4;
  __syncthreads();
  f32x4 qa = {0.f, 0.f, 0.f, 0.f};
  const float* wqp = wqk + jq;
  const float* qrow = lnq + s * 128;
  for (int c = 0; c < 128; ++c)
    qa += *(const f32x4*)(wqp + c * 128) * qrow[c];
  qa *= 0.08838834764831845f;  // 1/sqrt(128)
  u32x2 pk = { pkbf(qa[0], qa[1]), pkbf(qa[2], qa[3]) };
  *(u32x2*)(qout + b * 2048 + t * 4) = pk;
}

// ---- K2: dots(qa, xln) -> softmax -> p @ xln partials (single xln stream) ----
__global__ __launch_bounds__(256) void k2_attn(
    const unsigned short* __restrict__ xln, const unsigned short* __restrict__ qm,
    float* __restrict__ nump, float* __restrict__ denp) {
  const int nb = blockIdx.x, b = blockIdx.y;
  const int t = threadIdx.x, w = t >> 6, l = t & 63, lr = l & 15, lg = l >> 4;
  __shared__ __align__(16) unsigned short xT[4][4096];    // per-wave xln^T [128c][32n] swizzled
  __shared__ __align__(16) unsigned short pbuf[4][16*40]; // per-wave p^T

  const unsigned short* xb = xln + (long)b * (NTOT * CDIM);
  const unsigned short* qb = qm + b * 2048;

  short8 qf[4];
  #pragma unroll
  for (int kk = 0; kk < 4; ++kk)
    qf[kk] = *(const short8*)(qb + lr * CDIM + kk * 32 + lg * 8);

  f32x4 acc[8];
  #pragma unroll
  for (int i = 0; i < 8; ++i) acc[i] = (f32x4){0.f, 0.f, 0.f, 0.f};
  f32x4 dacc = {0.f, 0.f, 0.f, 0.f};

  const int base_n = nb * 512 + w * 32;
  char* xTc = (char*)&xT[w][0];
  unsigned short* pbw = &pbuf[w][0];
  const unsigned swz_rd = (((unsigned)lr >> 1) & 3u) << 4;  // read swizzle (per-lane const)

  short8 xk[2][8];
  #pragma unroll
  for (int h = 0; h < 2; ++h)
    #pragma unroll
    for (int kk = 0; kk < 4; ++kk)
      xk[0][h*4+kk] = *(const short8*)(xb + (long)(base_n + h*16 + lr) * CDIM + kk*32 + lg*8);

  #pragma unroll
  for (int it = 0; it < 4; ++it) {
    if (it < 3) {
      const int n1 = base_n + (it + 1) * 128;
      #pragma unroll
      for (int h = 0; h < 2; ++h)
        #pragma unroll
        for (int kk = 0; kk < 4; ++kk)
          xk[(it+1)&1][h*4+kk] = *(const short8*)(xb + (long)(n1 + h*16 + lr) * CDIM + kk*32 + lg*8);
    }
    // transpose current tile into xT: elem (c = kk*32+lg*8+e, n = h*16+lr)
    // layout: byte = c*64 + n*2, XOR-swizzled by ((c>>1)&3)<<4
    #pragma unroll
    for (int r = 0; r < 8; ++r) {
      const int h = r >> 2, kk = r & 3;
      const unsigned wb = (unsigned)(kk * 2048 + lg * 512 + (h * 16 + lr) * 2);
      #pragma unroll
      for (int e = 0; e < 8; ++e) {
        unsigned off = (wb + e * 64) ^ ((((unsigned)e >> 1) & 3u) << 4);
        *(unsigned short*)(xTc + off) = (unsigned short)xk[it&1][r][e];
      }
    }
    // dots: D[s][n] per 16-n half
    #pragma unroll
    for (int h = 0; h < 2; ++h) {
      f32x4 d = {0.f, 0.f, 0.f, 0.f};
      #pragma unroll
      for (int kk = 0; kk < 4; ++kk)
        d = __builtin_amdgcn_mfma_f32_16x16x32_bf16(qf[kk], xk[it&1][h*4+kk], d, 0, 0, 0);
      float e0 = __expf(d[0]), e1 = __expf(d[1]), e2 = __expf(d[2]), e3 = __expf(d[3]);
      float cs = e0 + e1 + e2 + e3;
      cs += __shfl_xor(cs, 16);
      cs += __shfl_xor(cs, 32);
      float inv = 1.f / cs;
      float p0 = e0 * inv + 1e-8f, p1 = e1 * inv + 1e-8f,
            p2 = e2 * inv + 1e-8f, p3 = e3 * inv + 1e-8f;
      dacc[0] += p0; dacc[1] += p1; dacc[2] += p2; dacc[3] += p3;
      unsigned w01 = pkbf(p0, p1), w23 = pkbf(p2, p3);
      const int nn = h * 16 + lr;
      pbw[(lg*4 + 0) * 40 + nn] = (unsigned short)w01;
      pbw[(lg*4 + 1) * 40 + nn] = (unsigned short)(w01 >> 16);
      pbw[(lg*4 + 2) * 40 + nn] = (unsigned short)w23;
      pbw[(lg*4 + 3) * 40 + nn] = (unsigned short)(w23 >> 16);
    }
    asm volatile("" ::: "memory");  // LDS writes (xT, pbuf) before reads; same-wave in-order
    short8 pf = *(const short8*)(pbw + lr * 40 + lg * 8);  // B-frag col=s, k=n
    #pragma unroll
    for (int ct = 0; ct < 8; ++ct) {
      // A-frag row c = ct*16+lr, k n = lg*8..+7 from xT (swizzled)
      unsigned off = ((unsigned)((ct*16 + lr) * 64 + lg * 16)) ^ swz_rd;
      short8 af = *(const short8*)(xTc + off);
      acc[ct] = __builtin_amdgcn_mfma_f32_16x16x32_bf16(af, pf, acc[ct], 0, 0, 0);
    }
    asm volatile("" ::: "memory");  // WAR: next tile's xT writes after these reads
  }

  #pragma unroll
  for (int m = 1; m <= 8; m <<= 1) {
    dacc[0] += __shfl_xor(dacc[0], m); dacc[1] += __shfl_xor(dacc[1], m);
    dacc[2] += __shfl_xor(dacc[2], m); dacc[3] += __shfl_xor(dacc[3], m);
  }
  float* outp = nump + (((long)b * 32 + nb) * 4 + w) * 2048;
  #pragma unroll
  for (int ct = 0; ct < 8; ++ct)
    *(f32x4*)(outp + lr * 128 + ct * 16 + lg * 4) = acc[ct];  // [s][c]
  if (lr == 0) {
    #pragma unroll
    for (int r = 0; r < 4; ++r)
      denp[(((long)b * 32 + nb) * 4 + w) * 16 + lg * 4 + r] = dacc[r];
  }
}

// ---- K3: reduce -> /den -> @Wv -> GRU -> MLP -> slots (+ qa next) ----
__global__ __launch_bounds__(128) void k3_update(
    const float* __restrict__ sprev, const float* __restrict__ nump,
    const float* __restrict__ denp, const float* __restrict__ Wv,
    const float* __restrict__ wih, const float* __restrict__ whh,
    const float* __restrict__ bih, const float* __restrict__ bhh,
    const float* __restrict__ w1, const float* __restrict__ b1,
    const float* __restrict__ w2, const float* __restrict__ b2,
    const float* __restrict__ lnfg, const float* __restrict__ lnfb,
    const float* __restrict__ lnsg, const float* __restrict__ lnsb,
    const float* __restrict__ wqk,
    float* __restrict__ sout, unsigned short* __restrict__ qout, const int doq) {
  const int g = blockIdx.x, b = blockIdx.y, t = threadIdx.x;
  const int sl = t >> 5, jq = (t & 31) * 4;
  const int s = g * 4 + sl;
  const long base = (long)b * 2048 + g * 512;
  __shared__ __align__(16) float sp[512];
  __shared__ __align__(16) float upd[512];   // nx = num/den
  __shared__ __align__(16) float upd2[512];  // updates = nx @ Wv
  __shared__ __align__(16) float lnb[512];
  __shared__ __align__(16) float denred[2][4];

  f32x4 dv = *(const f32x4*)(denp + ((long)b * 128 + t) * 16 + g * 4);
  #pragma unroll
  for (int m = 1; m <= 32; m <<= 1) {
    dv[0] += __shfl_xor(dv[0], m); dv[1] += __shfl_xor(dv[1], m);
    dv[2] += __shfl_xor(dv[2], m); dv[3] += __shfl_xor(dv[3], m);
  }
  if ((t & 63) == 0) *(f32x4*)denred[t >> 6] = dv;

  f32x4 hp4 = *(const f32x4*)(sprev + base + t * 4);
  *(f32x4*)(sp + t * 4) = hp4;

  f32x4 ns = {0.f, 0.f, 0.f, 0.f};
  const float* np = nump + (long)b * 262144 + s * 128 + jq;
  #pragma unroll 4
  for (int p = 0; p < 128; ++p) ns += *(const f32x4*)(np + (long)p * 2048);
  __syncthreads();
  float den_s = denred[0][sl] + denred[1][sl];
  *(f32x4*)(upd + t * 4) = ns * (1.f / den_s);
  __syncthreads();

  // updates = nx @ Wv
  f32x4 ud = {0,0,0,0};
  const float* nxr = upd + sl * 128;
  for (int c = 0; c < 128; ++c)
    ud += *(const f32x4*)(Wv + c * 128 + jq) * nxr[c];
  *(f32x4*)(upd2 + t * 4) = ud;
  __syncthreads();

  // GRU
  f32x4 ir = {0,0,0,0}, iz = {0,0,0,0}, inn = {0,0,0,0};
  f32x4 hr = {0,0,0,0}, hz = {0,0,0,0}, hn = {0,0,0,0};
  const float* wih_p = wih + jq;
  const float* whh_p = whh + jq;
  const float* ur  = upd2 + sl * 128;
  const float* hrw = sp + sl * 128;
  for (int c = 0; c < 128; ++c) {
    float u = ur[c], h = hrw[c];
    ir  += *(const f32x4*)(wih_p + c * 384)       * u;
    iz  += *(const f32x4*)(wih_p + c * 384 + 128) * u;
    inn += *(const f32x4*)(wih_p + c * 384 + 256) * u;
    hr  += *(const f32x4*)(whh_p + c * 384)       * h;
    hz  += *(const f32x4*)(whh_p + c * 384 + 128) * h;
    hn  += *(const f32x4*)(whh_p + c * 384 + 256) * h;
  }
  ir  += *(const f32x4*)(bih + jq);
  iz  += *(const f32x4*)(bih + 128 + jq);
  inn += *(const f32x4*)(bih + 256 + jq);
  hr  += *(const f32x4*)(bhh + jq);
  hz  += *(const f32x4*)(bhh + 128 + jq);
  hn  += *(const f32x4*)(bhh + 256 + jq);
  f32x4 snew;
  #pragma unroll
  for (int i = 0; i < 4; ++i) {
    float r = sigf(ir[i] + hr[i]);
    float z = sigf(iz[i] + hz[i]);
    float n = tanhfast(inn[i] + r * hn[i]);
    snew[i] = (1.f - z) * n + z * hp4[i];
  }

  float ps = snew[0] + snew[1] + snew[2] + snew[3];
  float pq = snew[0]*snew[0] + snew[1]*snew[1] + snew[2]*snew[2] + snew[3]*snew[3];
  ps += __shfl_xor(ps, 1); ps += __shfl_xor(ps, 2); ps += __shfl_xor(ps, 4); ps += __shfl_xor(ps, 8); ps += __shfl_xor(ps, 16);
  pq += __shfl_xor(pq, 1); pq += __shfl_xor(pq, 2); pq += __shfl_xor(pq, 4); pq += __shfl_xor(pq, 8); pq += __shfl_xor(pq, 16);
  float mean = ps * (1.f / 128.f);
  float var  = pq * (1.f / 128.f) - mean * mean;
  float rstd = rsqrtf(var + 1e-5f);
  f32x4 lf = (snew - mean) * rstd * (*(const f32x4*)(lnfg + jq)) + (*(const f32x4*)(lnfb + jq));
  *(f32x4*)(lnb + t * 4) = lf;
  __syncthreads();

  f32x4 ha = {0,0,0,0};
  const float* w1p = w1 + jq;
  const float* lrow = lnb + sl * 128;
  for (int c = 0; c < 128; ++c)
    ha += *(const f32x4*)(w1p + c * 128) * lrow[c];
  ha += *(const f32x4*)(b1 + jq);
  #pragma unroll
  for (int i = 0; i < 4; ++i) ha[i] = fmaxf(ha[i], 0.f);
  *(f32x4*)(upd + t * 4) = ha;
  __syncthreads();

  f32x4 oa = {0,0,0,0};
  const float* w2p = w2 + jq;
  const float* hrow = upd + sl * 128;
  for (int c = 0; c < 128; ++c)
    oa += *(const f32x4*)(w2p + c * 128) * hrow[c];
  oa += *(const f32x4*)(b2 + jq);
  f32x4 sf = snew + oa;
  *(f32x4*)(sout + base + t * 4) = sf;

  if (doq) {
    float qs = sf[0] + sf[1] + sf[2] + sf[3];
    float qz = sf[0]*sf[0] + sf[1]*sf[1] + sf[2]*sf[2] + sf[3]*sf[3];
    qs += __shfl_xor(qs, 1); qs += __shfl_xor(qs, 2); qs += __shfl_xor(qs, 4); qs += __shfl_xor(qs, 8); qs += __shfl_xor(qs, 16);
    qz += __shfl_xor(qz, 1); qz += __shfl_xor(qz, 2); qz += __shfl_xor(qz, 4); qz += __shfl_xor(qz, 8); qz += __shfl_xor(qz, 16);
    float m2 = qs * (1.f / 128.f);
    float v2 = qz * (1.f / 128.f) - m2 * m2;
    float rs2 = rsqrtf(v2 + 1e-5f);
    f32x4 lq = (sf - m2) * rs2 * (*(const f32x4*)(lnsg + jq)) + (*(const f32x4*)(lnsb + jq));
    *(f32x4*)(sp + t * 4) = lq;
    __syncthreads();
    f32x4 qa = {0,0,0,0};
    const float* wqp = wqk + jq;
    const float* qrow = sp + sl * 128;
    for (int c = 0; c < 128; ++c)
      qa += *(const f32x4*)(wqp + c * 128) * qrow[c];
    qa *= 0.08838834764831845f;
    u32x2 pk = { pkbf(qa[0], qa[1]), pkbf(qa[2], qa[3]) };
    *(u32x2*)(qout + base + t * 4) = pk;
  }
}

extern "C" void kernel_launch(void* const* d_in, const int* in_sizes, int n_in,
                              void* d_out, int out_size, void* d_ws, size_t ws_size,
                              hipStream_t stream) {
  (void)in_sizes; (void)n_in; (void)out_size; (void)ws_size;
  const float* slots = (const float*)d_in[0];
  const float* inputs = (const float*)d_in[1];
  const float* Wq  = (const float*)d_in[2];
  const float* Wk  = (const float*)d_in[3];
  const float* Wv  = (const float*)d_in[4];
  const float* wih = (const float*)d_in[5];
  const float* whh = (const float*)d_in[6];
  const float* bih = (const float*)d_in[7];
  const float* bhh = (const float*)d_in[8];
  const float* w1  = (const float*)d_in[9];
  const float* b1  = (const float*)d_in[10];
  const float* w2  = (const float*)d_in[11];
  const float* b2  = (const float*)d_in[12];
  const float* lnig = (const float*)d_in[13];
  const float* lnib = (const float*)d_in[14];
  const float* lnsg = (const float*)d_in[15];
  const float* lnsb = (const float*)d_in[16];
  const float* lnfg = (const float*)d_in[17];
  const float* lnfb = (const float*)d_in[18];

  char* ws = (char*)d_ws;
  unsigned short* xln  = (unsigned short*)(ws);
  unsigned short* qbuf = (unsigned short*)(ws + 134217728L);
  float* wqk  = (float*)(ws + 134348800L);
  float* nump = (float*)(ws + 134414336L);
  float* denp = (float*)(ws + 167968768L);
  float* sbuf = (float*)(ws + 168230912L);

  k0_wqk<<<64, 256, 0, stream>>>(Wq, Wk, wqk);
  k1_ln<<<8192, 256, 0, stream>>>(inputs, lnig, lnib, xln);
  kq_init<<<32, 512, 0, stream>>>(slots, lnsg, lnsb, wqk, qbuf);
  for (int it = 0; it < 3; ++it) {
    k2_attn<<<dim3(32, 32), 256, 0, stream>>>(xln, qbuf, nump, denp);
    const float* sprev = (it == 0) ? slots : sbuf;
    float* sdst = (it == 2) ? (float*)d_out : sbuf;
    k3_update<<<dim3(4, 32), 128, 0, stream>>>(sprev, nump, denp, Wv,
                                      wih, whh, bih, bhh, w1, b1, w2, b2,
                                      lnfg, lnfb, lnsg, lnsb, wqk,
                                      sdst, qbuf, (it < 2) ? 1 : 0);
  }
}